// Round 1
// baseline (1394.362 us; speedup 1.0000x reference)
//
#include <hip/hip_runtime.h>
#include <math.h>

#define TPB 256
#define NGRAPH 2048

// ---------------- init / degree / histograms ----------------
__global__ void k_init(float* __restrict__ deg, int* __restrict__ cnt,
                       int* __restrict__ cntg, int N) {
  int i = blockIdx.x * TPB + threadIdx.x;
  if (i < N) { deg[i] = 1.0f; cnt[i] = 0; }
  if (i < NGRAPH) cntg[i] = 0;
}

__global__ void k_deg_hist(const int* __restrict__ dst, float* __restrict__ deg,
                           int* __restrict__ cnt, int E) {
  int e = blockIdx.x * TPB + threadIdx.x;
  if (e < E) {
    int d = dst[e];
    atomicAdd(&deg[d], 1.0f);
    atomicAdd(&cnt[d], 1);
  }
}

__global__ void k_hist_batch(const int* __restrict__ batch, int* __restrict__ cntg, int N) {
  int i = blockIdx.x * TPB + threadIdx.x;
  if (i < N) atomicAdd(&cntg[batch[i]], 1);
}

__global__ void k_rsqrt(float* __restrict__ d, int N) {
  int i = blockIdx.x * TPB + threadIdx.x;
  if (i < N) d[i] = rsqrtf(d[i]);
}

// ---------------- scans (for CSR row_start and graph starts) ----------------
// per-block scan of 1024 elems (256 thr x 4), writes local-exclusive + block sum
__global__ void k_scan1(const int* __restrict__ in, int* __restrict__ out,
                        int* __restrict__ bsum, int n) {
  __shared__ int ts[256];
  int tid = threadIdx.x;
  int base = blockIdx.x * 1024 + tid * 4;
  int v0 = (base + 0 < n) ? in[base + 0] : 0;
  int v1 = (base + 1 < n) ? in[base + 1] : 0;
  int v2 = (base + 2 < n) ? in[base + 2] : 0;
  int v3 = (base + 3 < n) ? in[base + 3] : 0;
  int s = v0 + v1 + v2 + v3;
  int run = s;
  ts[tid] = run; __syncthreads();
  for (int off = 1; off < 256; off <<= 1) {
    int add = (tid >= off) ? ts[tid - off] : 0;
    __syncthreads();
    run += add; ts[tid] = run; __syncthreads();
  }
  int acc = run - s;
  if (base + 0 < n) out[base + 0] = acc; acc += v0;
  if (base + 1 < n) out[base + 1] = acc; acc += v1;
  if (base + 2 < n) out[base + 2] = acc; acc += v2;
  if (base + 3 < n) out[base + 3] = acc;
  if (tid == 255) bsum[blockIdx.x] = run;
}

// single-block exclusive scan (n <= 2048), writes dst[n] = total
__global__ void k_scan_small(const int* __restrict__ in, int* __restrict__ dst, int n) {
  __shared__ int ts[256];
  int tid = threadIdx.x;
  int chunk = (n + 255) >> 8;
  int start = tid * chunk;
  int s = 0;
  for (int j = 0; j < chunk; ++j) { int idx = start + j; if (idx < n) s += in[idx]; }
  int run = s;
  ts[tid] = run; __syncthreads();
  for (int off = 1; off < 256; off <<= 1) {
    int add = (tid >= off) ? ts[tid - off] : 0;
    __syncthreads();
    run += add; ts[tid] = run; __syncthreads();
  }
  int acc = run - s;
  for (int j = 0; j < chunk; ++j) {
    int idx = start + j;
    if (idx < n) { dst[idx] = acc; acc += in[idx]; }
  }
  if (tid == 255) dst[n] = run;
}

__global__ void k_scan3(int* __restrict__ rs, const int* __restrict__ bsumx,
                        int* __restrict__ cursor, int n, int total) {
  int i = blockIdx.x * TPB + threadIdx.x;
  if (i < n) {
    int v = rs[i] + bsumx[i >> 10];
    rs[i] = v; cursor[i] = v;
  }
  if (i == 0) rs[n] = total;
}

__global__ void k_scatter(const int* __restrict__ src, const int* __restrict__ dst,
                          int* __restrict__ cursor, int* __restrict__ es, int E) {
  int e = blockIdx.x * TPB + threadIdx.x;
  if (e < E) {
    int d = dst[e];
    int p = atomicAdd(&cursor[d], 1);
    es[p] = src[e];
  }
}

// ---------------- layer-1 aggregation on D=8 ----------------
__global__ void k_agg8(const float* __restrict__ x, const float* __restrict__ dis,
                       const int* __restrict__ rs, const int* __restrict__ es,
                       float* __restrict__ xa8, int N) {
  int t = blockIdx.x * TPB + threadIdx.x;
  int n = t >> 3, c = t & 7;
  if (n >= N) return;
  int e0 = rs[n], e1 = rs[n + 1];
  float acc = 0.f;
  for (int e = e0; e < e1; ++e) {
    int s = es[e];
    acc += dis[s] * x[s * 8 + c];
  }
  float dn = dis[n];
  xa8[n * 8 + c] = dn * acc + dn * dn * x[n * 8 + c];
}

// y[N,256] = xa8[N,8] @ W[8,256] + b
__global__ __launch_bounds__(256) void k_gemm8(const float* __restrict__ A,
    const float* __restrict__ W, const float* __restrict__ b,
    float* __restrict__ Y, int N) {
  __shared__ float Ws[8 * 256];
  __shared__ float bs[256];
  __shared__ float rows[64 * 8];
  int tid = threadIdx.x;
  int row0 = blockIdx.x * 64;
  for (int j = 0; j < 8; ++j) Ws[tid + j * 256] = W[tid + j * 256];
  bs[tid] = b[tid];
  int lim = N * 8;
  int o0 = row0 * 8 + tid, o1 = o0 + 256;
  rows[tid] = (o0 < lim) ? A[o0] : 0.f;
  rows[tid + 256] = (o1 < lim) ? A[o1] : 0.f;
  __syncthreads();
  for (int r = 0; r < 64; ++r) {
    int row = row0 + r;
    if (row >= N) break;
    float acc = bs[tid];
#pragma unroll
    for (int k = 0; k < 8; ++k) acc += rows[r * 8 + k] * Ws[k * 256 + tid];
    Y[(size_t)row * 256 + tid] = acc;
  }
}

// ---------------- H=256 aggregation: one block per node ----------------
__global__ __launch_bounds__(256) void k_agg256(const float* __restrict__ h,
    const float* __restrict__ dis, const int* __restrict__ rs,
    const int* __restrict__ es, float* __restrict__ xa, int N) {
  int n = blockIdx.x;
  int c = threadIdx.x;
  int e0 = rs[n], e1 = rs[n + 1];
  float acc = 0.f;
  for (int e = e0; e < e1; ++e) {
    int s = es[e];
    acc += dis[s] * h[(size_t)s * 256 + c];
  }
  float dn = dis[n];
  xa[(size_t)n * 256 + c] = dn * acc + dn * dn * h[(size_t)n * 256 + c];
}

// ---------------- fp32 GEMM: Y[N,256] = A[N,256] @ W[256,256] + b ----------------
#define GBM 128
#define GBN 128
#define GBK 16
__global__ __launch_bounds__(256) void k_gemm256(const float* __restrict__ A,
    const float* __restrict__ W, const float* __restrict__ bias,
    float* __restrict__ Y, int N) {
  __shared__ float As[GBK][GBM + 4];
  __shared__ float Bs[GBK][GBN + 4];
  const int tid = threadIdx.x;
  const int row0 = blockIdx.x * GBM;
  const int col0 = blockIdx.y * GBN;
  const int tr = tid >> 4;         // 0..15, 8 rows each
  const int tc = tid & 15;         // 0..15, 8 cols each
  const int arow = tid >> 2;       // 0..63
  const int ak = (tid & 3) << 2;   // 0,4,8,12
  const int wk = tid >> 5;         // 0..7
  const int wc = (tid & 31) << 2;  // 0..124

  float acc[8][8] = {};
  const bool a0ok = (row0 + arow) < N;
  const bool a1ok = (row0 + arow + 64) < N;
  const float* Ap0 = A + (size_t)(row0 + arow) * 256 + ak;
  const float* Ap1 = Ap0 + 64 * 256;

  for (int k0 = 0; k0 < 256; k0 += GBK) {
    float4 av0 = a0ok ? *(const float4*)(Ap0 + k0) : make_float4(0.f, 0.f, 0.f, 0.f);
    float4 av1 = a1ok ? *(const float4*)(Ap1 + k0) : make_float4(0.f, 0.f, 0.f, 0.f);
    float4 wv0 = *(const float4*)(W + (size_t)(k0 + wk) * 256 + col0 + wc);
    float4 wv1 = *(const float4*)(W + (size_t)(k0 + wk + 8) * 256 + col0 + wc);
    __syncthreads();
    As[ak + 0][arow] = av0.x; As[ak + 1][arow] = av0.y;
    As[ak + 2][arow] = av0.z; As[ak + 3][arow] = av0.w;
    As[ak + 0][arow + 64] = av1.x; As[ak + 1][arow + 64] = av1.y;
    As[ak + 2][arow + 64] = av1.z; As[ak + 3][arow + 64] = av1.w;
    *(float4*)&Bs[wk][wc] = wv0;
    *(float4*)&Bs[wk + 8][wc] = wv1;
    __syncthreads();
#pragma unroll
    for (int kk = 0; kk < GBK; ++kk) {
      float4 a0 = *(const float4*)&As[kk][tr * 8];
      float4 a1 = *(const float4*)&As[kk][tr * 8 + 4];
      float4 b0 = *(const float4*)&Bs[kk][tc * 8];
      float4 b1 = *(const float4*)&Bs[kk][tc * 8 + 4];
      float a[8] = {a0.x, a0.y, a0.z, a0.w, a1.x, a1.y, a1.z, a1.w};
      float bf[8] = {b0.x, b0.y, b0.z, b0.w, b1.x, b1.y, b1.z, b1.w};
#pragma unroll
      for (int i = 0; i < 8; ++i)
#pragma unroll
        for (int j = 0; j < 8; ++j)
          acc[i][j] = fmaf(a[i], bf[j], acc[i][j]);
    }
  }
  float4 bb0 = *(const float4*)&bias[col0 + tc * 8];
  float4 bb1 = *(const float4*)&bias[col0 + tc * 8 + 4];
#pragma unroll
  for (int i = 0; i < 8; ++i) {
    int r = row0 + tr * 8 + i;
    if (r < N) {
      float4 o0, o1;
      o0.x = acc[i][0] + bb0.x; o0.y = acc[i][1] + bb0.y;
      o0.z = acc[i][2] + bb0.z; o0.w = acc[i][3] + bb0.w;
      o1.x = acc[i][4] + bb1.x; o1.y = acc[i][5] + bb1.y;
      o1.z = acc[i][6] + bb1.z; o1.w = acc[i][7] + bb1.w;
      *(float4*)&Y[(size_t)r * 256 + col0 + tc * 8] = o0;
      *(float4*)&Y[(size_t)r * 256 + col0 + tc * 8 + 4] = o1;
    }
  }
}

// ---------------- BN stats / scale-shift / normalize ----------------
__global__ void k_zero(float* __restrict__ p, int n) {
  int i = blockIdx.x * TPB + threadIdx.x;
  if (i < n) p[i] = 0.f;
}

__global__ __launch_bounds__(256) void k_stats(const float* __restrict__ Y,
                                               float* __restrict__ stats, int N) {
  int c = threadIdx.x;
  float s = 0.f, s2 = 0.f;
  for (int r = blockIdx.x; r < N; r += gridDim.x) {
    float v = Y[(size_t)r * 256 + c];
    s += v; s2 += v * v;
  }
  atomicAdd(&stats[c], s);
  atomicAdd(&stats[256 + c], s2);
}

__global__ void k_scaleshift(const float* __restrict__ stats, const float* __restrict__ g,
                             const float* __restrict__ be, float* __restrict__ ss, int N) {
  int c = threadIdx.x;
  float inv = 1.0f / (float)N;
  float mean = stats[c] * inv;
  float var = stats[256 + c] * inv - mean * mean;
  var = fmaxf(var, 0.f);
  float sc = g[c] * rsqrtf(var + 1e-5f);
  ss[c] = sc;
  ss[256 + c] = be[c] - mean * sc;
}

__global__ void k_norm(float* __restrict__ Y, const float* __restrict__ ss, int n4) {
  int stride = gridDim.x * blockDim.x;
  for (int i = blockIdx.x * blockDim.x + threadIdx.x; i < n4; i += stride) {
    int c4 = (i & 63) << 2;
    float4 v = ((const float4*)Y)[i];
    float4 sc = *(const float4*)&ss[c4];
    float4 sh = *(const float4*)&ss[256 + c4];
    v.x = fmaxf(v.x * sc.x + sh.x, 0.f);
    v.y = fmaxf(v.y * sc.y + sh.y, 0.f);
    v.z = fmaxf(v.z * sc.z + sh.z, 0.f);
    v.w = fmaxf(v.w * sc.w + sh.w, 0.f);
    ((float4*)Y)[i] = v;
  }
}

// ---------------- pooling (batch is sorted) ----------------
__global__ __launch_bounds__(256) void k_pool(const float* __restrict__ H,
    const int* __restrict__ gstart, float* __restrict__ pooled) {
  int g = blockIdx.x, c = threadIdx.x;
  int n0 = gstart[g], n1 = gstart[g + 1];
  float s = 0.f, m = 0.f;  // h >= 0 post-ReLU, so 0 is a valid max identity
  for (int n = n0; n < n1; ++n) {
    float v = H[(size_t)n * 256 + c];
    s += v; m = fmaxf(m, v);
  }
  float cnt = (float)(n1 - n0);
  pooled[g * 512 + c] = s / fmaxf(cnt, 1.0f);
  pooled[g * 512 + 256 + c] = m;
}

// ---------------- MLP + heads ----------------
__global__ __launch_bounds__(256) void k_mlp1(const float* __restrict__ P,
    const float* __restrict__ W, const float* __restrict__ b, float* __restrict__ O) {
  __shared__ float Ps[8 * 512];
  int tid = threadIdx.x;
  int g0 = blockIdx.x * 8;
  for (int j = 0; j < 16; ++j) Ps[tid + j * 256] = P[g0 * 512 + tid + j * 256];
  __syncthreads();
  float acc[8];
  float bb = b[tid];
#pragma unroll
  for (int gi = 0; gi < 8; ++gi) acc[gi] = bb;
  for (int k = 0; k < 512; ++k) {
    float w = W[k * 256 + tid];
#pragma unroll
    for (int gi = 0; gi < 8; ++gi) acc[gi] += Ps[gi * 512 + k] * w;
  }
  for (int gi = 0; gi < 8; ++gi)
    O[(g0 + gi) * 256 + tid] = fmaxf(acc[gi], 0.f);
}

__global__ __launch_bounds__(128) void k_mlp2(const float* __restrict__ S,
    const float* __restrict__ W, const float* __restrict__ b, float* __restrict__ O) {
  __shared__ float Ss[16 * 256];
  int tid = threadIdx.x;
  int g0 = blockIdx.x * 16;
  for (int j = 0; j < 32; ++j) Ss[tid + j * 128] = S[g0 * 256 + tid + j * 128];
  __syncthreads();
  float acc[16];
  float bb = b[tid];
#pragma unroll
  for (int gi = 0; gi < 16; ++gi) acc[gi] = bb;
  for (int k = 0; k < 256; ++k) {
    float w = W[k * 128 + tid];
#pragma unroll
    for (int gi = 0; gi < 16; ++gi) acc[gi] += Ss[gi * 256 + k] * w;
  }
  for (int gi = 0; gi < 16; ++gi)
    O[(g0 + gi) * 128 + tid] = fmaxf(acc[gi], 0.f);
}

__global__ __launch_bounds__(128) void k_heads(const float* __restrict__ S,
    const float* __restrict__ hW1, const float* __restrict__ hb1,
    const float* __restrict__ hW2, const float* __restrict__ hb2,
    float* __restrict__ out) {
  __shared__ float ssm[128];
  __shared__ float t1[96];
  int g = blockIdx.x, tid = threadIdx.x;
  ssm[tid] = S[g * 128 + tid];
  __syncthreads();
  if (tid < 96) {
    int t = tid >> 5, o = tid & 31;
    float acc = hb1[t * 32 + o];
    for (int k = 0; k < 128; ++k) acc += ssm[k] * hW1[t * 4096 + k * 32 + o];
    t1[tid] = fmaxf(acc, 0.f);
  }
  __syncthreads();
  if (tid < 3) {
    float acc = hb2[tid];
    for (int o = 0; o < 32; ++o) acc += t1[tid * 32 + o] * hW2[tid * 32 + o];
    out[tid * NGRAPH + g] = acc;
  }
}

// ---------------- host launcher ----------------
extern "C" void kernel_launch(void* const* d_in, const int* in_sizes, int n_in,
                              void* d_out, int out_size, void* d_ws, size_t ws_size,
                              hipStream_t stream) {
  const float* x   = (const float*)d_in[0];
  const int* ei    = (const int*)d_in[1];
  const int* batch = (const int*)d_in[2];
  const float* W1 = (const float*)d_in[3];  const float* b1 = (const float*)d_in[4];
  const float* W2 = (const float*)d_in[5];  const float* b2 = (const float*)d_in[6];
  const float* W3 = (const float*)d_in[7];  const float* b3 = (const float*)d_in[8];
  const float* W4 = (const float*)d_in[9];  const float* b4 = (const float*)d_in[10];
  const float* g1 = (const float*)d_in[11]; const float* be1 = (const float*)d_in[12];
  const float* g2 = (const float*)d_in[13]; const float* be2 = (const float*)d_in[14];
  const float* g3 = (const float*)d_in[15]; const float* be3 = (const float*)d_in[16];
  const float* g4 = (const float*)d_in[17]; const float* be4 = (const float*)d_in[18];
  const float* sW1 = (const float*)d_in[19]; const float* sb1 = (const float*)d_in[20];
  const float* sW2 = (const float*)d_in[21]; const float* sb2 = (const float*)d_in[22];
  const float* hW1 = (const float*)d_in[23]; const float* hb1 = (const float*)d_in[24];
  const float* hW2 = (const float*)d_in[25]; const float* hb2 = (const float*)d_in[26];

  const int N = in_sizes[0] / 8;
  const int E = in_sizes[1] / 2;
  const int* srcp = ei;
  const int* dstp = ei + E;

  char* base = (char*)d_ws;
  size_t off = 0;
  auto alloc = [&](size_t bytes) -> void* {
    void* p = base + off;
    off += (bytes + 255) & ~(size_t)255;
    return p;
  };
  float* BUF0 = (float*)alloc((size_t)N * 256 * 4);
  float* BUF1 = (float*)alloc((size_t)N * 256 * 4);
  float* dis  = (float*)alloc((size_t)N * 4);
  int* cnt    = (int*)alloc((size_t)N * 4);
  int* rs     = (int*)alloc((size_t)(N + 1) * 4);
  int* cursor = (int*)alloc((size_t)N * 4);
  int* es     = (int*)alloc((size_t)E * 4);
  int* bsum   = (int*)alloc(1024 * 4);
  int* bsumx  = (int*)alloc(1032 * 4);
  float* xa8  = (float*)alloc((size_t)N * 8 * 4);
  float* stats = (float*)alloc(512 * 4);
  float* ss    = (float*)alloc(512 * 4);
  int* cntg    = (int*)alloc(2048 * 4);
  int* gstart  = (int*)alloc(2049 * 4);
  float* pooled = (float*)alloc((size_t)2048 * 512 * 4);
  float* s1b    = (float*)alloc((size_t)2048 * 256 * 4);
  float* s2b    = (float*)alloc((size_t)2048 * 128 * 4);
  (void)ws_size; (void)n_in; (void)out_size;

  int nb = (N + TPB - 1) / TPB;
  int eb = (E + TPB - 1) / TPB;
  int nblocks1 = (N + 1023) / 1024;

  k_init<<<nb, TPB, 0, stream>>>(dis, cnt, cntg, N);
  k_deg_hist<<<eb, TPB, 0, stream>>>(dstp, dis, cnt, E);
  k_hist_batch<<<nb, TPB, 0, stream>>>(batch, cntg, N);
  k_rsqrt<<<nb, TPB, 0, stream>>>(dis, N);
  k_scan1<<<nblocks1, 256, 0, stream>>>(cnt, rs, bsum, N);
  k_scan_small<<<1, 256, 0, stream>>>(bsum, bsumx, nblocks1);
  k_scan3<<<nb, TPB, 0, stream>>>(rs, bsumx, cursor, N, E);
  k_scatter<<<eb, TPB, 0, stream>>>(srcp, dstp, cursor, es, E);
  k_scan_small<<<1, 256, 0, stream>>>(cntg, gstart, NGRAPH);

  // ---- layer 1 (aggregate on D=8, then project) ----
  k_agg8<<<(N * 8 + TPB - 1) / TPB, TPB, 0, stream>>>(x, dis, rs, es, xa8, N);
  k_gemm8<<<(N + 63) / 64, 256, 0, stream>>>(xa8, W1, b1, BUF0, N);
  k_zero<<<2, TPB, 0, stream>>>(stats, 512);
  k_stats<<<1024, 256, 0, stream>>>(BUF0, stats, N);
  k_scaleshift<<<1, 256, 0, stream>>>(stats, g1, be1, ss, N);
  k_norm<<<2048, 256, 0, stream>>>(BUF0, ss, N * 64);

  // ---- layers 2..4 ----
  const float* Ws[3]  = {W2, W3, W4};
  const float* bs_[3] = {b2, b3, b4};
  const float* gs[3]  = {g2, g3, g4};
  const float* bes[3] = {be2, be3, be4};
  for (int L = 0; L < 3; ++L) {
    k_agg256<<<N, 256, 0, stream>>>(BUF0, dis, rs, es, BUF1, N);
    dim3 gg((N + GBM - 1) / GBM, 256 / GBN);
    k_gemm256<<<gg, 256, 0, stream>>>(BUF1, Ws[L], bs_[L], BUF0, N);
    k_zero<<<2, TPB, 0, stream>>>(stats, 512);
    k_stats<<<1024, 256, 0, stream>>>(BUF0, stats, N);
    k_scaleshift<<<1, 256, 0, stream>>>(stats, gs[L], bes[L], ss, N);
    k_norm<<<2048, 256, 0, stream>>>(BUF0, ss, N * 64);
  }

  // ---- pooling + MLP + heads ----
  k_pool<<<NGRAPH, 256, 0, stream>>>(BUF0, gstart, pooled);
  k_mlp1<<<NGRAPH / 8, 256, 0, stream>>>(pooled, sW1, sb1, s1b);
  k_mlp2<<<NGRAPH / 16, 128, 0, stream>>>(s1b, sW2, sb2, s2b);
  k_heads<<<NGRAPH, 128, 0, stream>>>(s2b, hW1, hb1, hW2, hb2, (float*)d_out);
}

// Round 2
// 852.744 us; speedup vs baseline: 1.6351x; 1.6351x over previous
//
#include <hip/hip_runtime.h>
#include <math.h>

#define TPB 256
#define NGRAPH 2048

typedef __attribute__((ext_vector_type(8))) short bf16x8;
typedef __attribute__((ext_vector_type(4))) float f32x4;

__device__ __forceinline__ unsigned short f2bf(float f) {
  unsigned u = __float_as_uint(f);
  unsigned r = (u + 0x7FFF + ((u >> 16) & 1)) >> 16;
  return (unsigned short)r;
}
__device__ __forceinline__ float bf2f(unsigned short h) {
  return __uint_as_float(((unsigned)h) << 16);
}

#define GLOAD_LDS16(G, L) \
  __builtin_amdgcn_global_load_lds((const __attribute__((address_space(1))) unsigned int*)(G), \
                                   (__attribute__((address_space(3))) unsigned int*)(L), 16, 0, 0)

// ---------------- init / degree / histograms ----------------
__global__ void k_init(float* __restrict__ deg, int* __restrict__ cnt,
                       int* __restrict__ cntg, float* __restrict__ statsAll, int N) {
  int i = blockIdx.x * TPB + threadIdx.x;
  if (i < N) { deg[i] = 1.0f; cnt[i] = 0; }
  if (i < NGRAPH) cntg[i] = 0;
  if (i < 2048) statsAll[i] = 0.f;
}

__global__ void k_deg_hist(const int* __restrict__ dst, float* __restrict__ deg,
                           int* __restrict__ cnt, int E) {
  int e = blockIdx.x * TPB + threadIdx.x;
  if (e < E) {
    int d = dst[e];
    atomicAdd(&deg[d], 1.0f);
    atomicAdd(&cnt[d], 1);
  }
}

__global__ void k_hist_batch(const int* __restrict__ batch, int* __restrict__ cntg, int N) {
  int i = blockIdx.x * TPB + threadIdx.x;
  if (i < N) atomicAdd(&cntg[batch[i]], 1);
}

__global__ void k_rsqrt(float* __restrict__ d, int N) {
  int i = blockIdx.x * TPB + threadIdx.x;
  if (i < N) d[i] = rsqrtf(d[i]);
}

// ---------------- scans ----------------
__global__ void k_scan1(const int* __restrict__ in, int* __restrict__ out,
                        int* __restrict__ bsum, int n) {
  __shared__ int ts[256];
  int tid = threadIdx.x;
  int base = blockIdx.x * 1024 + tid * 4;
  int v0 = (base + 0 < n) ? in[base + 0] : 0;
  int v1 = (base + 1 < n) ? in[base + 1] : 0;
  int v2 = (base + 2 < n) ? in[base + 2] : 0;
  int v3 = (base + 3 < n) ? in[base + 3] : 0;
  int s = v0 + v1 + v2 + v3;
  int run = s;
  ts[tid] = run; __syncthreads();
  for (int off = 1; off < 256; off <<= 1) {
    int add = (tid >= off) ? ts[tid - off] : 0;
    __syncthreads();
    run += add; ts[tid] = run; __syncthreads();
  }
  int acc = run - s;
  if (base + 0 < n) out[base + 0] = acc; acc += v0;
  if (base + 1 < n) out[base + 1] = acc; acc += v1;
  if (base + 2 < n) out[base + 2] = acc; acc += v2;
  if (base + 3 < n) out[base + 3] = acc;
  if (tid == 255) bsum[blockIdx.x] = run;
}

__global__ void k_scan_small(const int* __restrict__ in, int* __restrict__ dst, int n) {
  __shared__ int ts[256];
  int tid = threadIdx.x;
  int chunk = (n + 255) >> 8;
  int start = tid * chunk;
  int s = 0;
  for (int j = 0; j < chunk; ++j) { int idx = start + j; if (idx < n) s += in[idx]; }
  int run = s;
  ts[tid] = run; __syncthreads();
  for (int off = 1; off < 256; off <<= 1) {
    int add = (tid >= off) ? ts[tid - off] : 0;
    __syncthreads();
    run += add; ts[tid] = run; __syncthreads();
  }
  int acc = run - s;
  for (int j = 0; j < chunk; ++j) {
    int idx = start + j;
    if (idx < n) { dst[idx] = acc; acc += in[idx]; }
  }
  if (tid == 255) dst[n] = run;
}

__global__ void k_scan3(int* __restrict__ rs, const int* __restrict__ bsumx,
                        int* __restrict__ cursor, int n, int total) {
  int i = blockIdx.x * TPB + threadIdx.x;
  if (i < n) {
    int v = rs[i] + bsumx[i >> 10];
    rs[i] = v; cursor[i] = v;
  }
  if (i == 0) rs[n] = total;
}

__global__ void k_scatter(const int* __restrict__ src, const int* __restrict__ dst,
                          int* __restrict__ cursor, int* __restrict__ es, int E) {
  int e = blockIdx.x * TPB + threadIdx.x;
  if (e < E) {
    int d = dst[e];
    int p = atomicAdd(&cursor[d], 1);
    es[p] = src[e];
  }
}

// ---------------- weight prep: transpose + hi/lo split ----------------
// Wt[c][k] = W[k][c]; block = column c, thread = k
__global__ __launch_bounds__(256) void k_wprep(const float* __restrict__ W,
    unsigned short* __restrict__ Wthi, unsigned short* __restrict__ Wtlo) {
  int c = blockIdx.x, k = threadIdx.x;
  float w = W[k * 256 + c];
  unsigned short h = f2bf(w);
  Wthi[c * 256 + k] = h;
  Wtlo[c * 256 + k] = f2bf(w - bf2f(h));
}

// ---------------- layer-1 aggregation on D=8 (fp32) ----------------
__global__ void k_agg8(const float* __restrict__ x, const float* __restrict__ dis,
                       const int* __restrict__ rs, const int* __restrict__ es,
                       float* __restrict__ xa8, int N) {
  int t = blockIdx.x * TPB + threadIdx.x;
  int n = t >> 3, c = t & 7;
  if (n >= N) return;
  int e0 = rs[n], e1 = rs[n + 1];
  float acc = 0.f;
  for (int e = e0; e < e1; ++e) {
    int s = es[e];
    acc += dis[s] * x[s * 8 + c];
  }
  float dn = dis[n];
  xa8[n * 8 + c] = dn * acc + dn * dn * x[n * 8 + c];
}

// y[N,256] = xa8[N,8] @ W[8,256] + b, fused BN stats
__global__ __launch_bounds__(256) void k_gemm8(const float* __restrict__ A,
    const float* __restrict__ W, const float* __restrict__ b,
    float* __restrict__ Y, float* __restrict__ stats, int N) {
  __shared__ float Ws[8 * 256];
  __shared__ float bs[256];
  __shared__ float rows[64 * 8];
  int tid = threadIdx.x;
  int row0 = blockIdx.x * 64;
  for (int j = 0; j < 8; ++j) Ws[tid + j * 256] = W[tid + j * 256];
  bs[tid] = b[tid];
  int lim = N * 8;
  int o0 = row0 * 8 + tid, o1 = o0 + 256;
  rows[tid] = (o0 < lim) ? A[o0] : 0.f;
  rows[tid + 256] = (o1 < lim) ? A[o1] : 0.f;
  __syncthreads();
  float s = 0.f, s2 = 0.f;
  for (int r = 0; r < 64; ++r) {
    int row = row0 + r;
    if (row >= N) break;
    float acc = bs[tid];
#pragma unroll
    for (int k = 0; k < 8; ++k) acc += rows[r * 8 + k] * Ws[k * 256 + tid];
    Y[(size_t)row * 256 + tid] = acc;
    s += acc; s2 += acc * acc;
  }
  atomicAdd(&stats[tid], s);
  atomicAdd(&stats[256 + tid], s2);
}

// ---------------- fused BN+ReLU aggregation, wave per node ----------------
// A_next[n] = dn * sum_s ds * relu(Y[s]*sc+sh) + dn^2 * relu(Y[n]*sc+sh)
// writes bf16 hi/lo planes
__global__ __launch_bounds__(256) void k_agg_bn(const float* __restrict__ Y,
    const float* __restrict__ ss, const float* __restrict__ dis,
    const int* __restrict__ rs, const int* __restrict__ es,
    unsigned short* __restrict__ Ahi, unsigned short* __restrict__ Alo, int N) {
  int lane = threadIdx.x & 63;
  int n = __builtin_amdgcn_readfirstlane(blockIdx.x * 4 + (threadIdx.x >> 6));
  if (n >= N) return;
  int c = lane * 4;
  float4 sc = *(const float4*)&ss[c];
  float4 sh = *(const float4*)&ss[256 + c];
  int e0 = rs[n], e1 = rs[n + 1];
  float4 a = make_float4(0.f, 0.f, 0.f, 0.f);
  for (int e = e0; e < e1; ++e) {
    int s = es[e];
    float d = dis[s];
    float4 y = *(const float4*)&Y[(size_t)s * 256 + c];
    a.x += d * fmaxf(fmaf(y.x, sc.x, sh.x), 0.f);
    a.y += d * fmaxf(fmaf(y.y, sc.y, sh.y), 0.f);
    a.z += d * fmaxf(fmaf(y.z, sc.z, sh.z), 0.f);
    a.w += d * fmaxf(fmaf(y.w, sc.w, sh.w), 0.f);
  }
  float dn = dis[n];
  float dn2 = dn * dn;
  float4 y = *(const float4*)&Y[(size_t)n * 256 + c];
  float4 r;
  r.x = dn * a.x + dn2 * fmaxf(fmaf(y.x, sc.x, sh.x), 0.f);
  r.y = dn * a.y + dn2 * fmaxf(fmaf(y.y, sc.y, sh.y), 0.f);
  r.z = dn * a.z + dn2 * fmaxf(fmaf(y.z, sc.z, sh.z), 0.f);
  r.w = dn * a.w + dn2 * fmaxf(fmaf(y.w, sc.w, sh.w), 0.f);
  ushort4 h, l;
  h.x = f2bf(r.x); l.x = f2bf(r.x - bf2f(h.x));
  h.y = f2bf(r.y); l.y = f2bf(r.y - bf2f(h.y));
  h.z = f2bf(r.z); l.z = f2bf(r.z - bf2f(h.z));
  h.w = f2bf(r.w); l.w = f2bf(r.w - bf2f(h.w));
  *(ushort4*)&Ahi[(size_t)n * 256 + c] = h;
  *(ushort4*)&Alo[(size_t)n * 256 + c] = l;
}

// ---------------- MFMA GEMM: Y[M,256] = (Ahi+Alo)[M,256] @ (Whi+Wlo)[256,256] + b
// 3-pass compensated bf16: Ah*Wh + Al*Wh + Ah*Wl. Fused BN stats.
// block: 256 thr = 4 waves (2x2), tile 128x128, BK=64, K=256
__global__ __launch_bounds__(256) void k_gemm_mfma(
    const unsigned short* __restrict__ Ahi, const unsigned short* __restrict__ Alo,
    const unsigned short* __restrict__ Wthi, const unsigned short* __restrict__ Wtlo,
    const float* __restrict__ bias, float* __restrict__ Y,
    float* __restrict__ stats, int M) {
  __shared__ unsigned short As[2][128 * 64];  // [plane][row*64 + k] (xor-swizzled 16B chunks)
  const int tid = threadIdx.x;
  const int lane = tid & 63;
  const int wid = tid >> 6;
  const int wr = wid >> 1, wc = wid & 1;
  const int l15 = lane & 15, lg = lane >> 4;
  const int row0 = blockIdx.x * 128;
  const int col0 = blockIdx.y * 128;

  f32x4 acc[4][4] = {};

  for (int k0 = 0; k0 < 256; k0 += 64) {
    __syncthreads();  // previous iter's LDS reads done
#pragma unroll
    for (int p = 0; p < 2; ++p) {
      const unsigned short* Ap = p ? Alo : Ahi;
#pragma unroll
      for (int it = 0; it < 4; ++it) {
        int L = it * 4096 + tid * 16;          // byte offset in 16KB plane
        int row = L >> 7;                      // 0..127
        int kb = L & 127;
        int skb = kb ^ ((row & 7) << 4);       // inverse-swizzled source (rule #21)
        GLOAD_LDS16(Ap + (size_t)(row0 + row) * 256 + k0 + (skb >> 1),
                    &As[p][L >> 1]);
      }
    }
    __syncthreads();  // drains vmcnt -> LDS visible
#pragma unroll
    for (int kk = 0; kk < 2; ++kk) {
      bf16x8 bh[4], bl[4];
#pragma unroll
      for (int n = 0; n < 4; ++n) {
        int col = col0 + wc * 64 + n * 16 + l15;
        int kidx = k0 + kk * 32 + lg * 8;
        bh[n] = *(const bf16x8*)(Wthi + (size_t)col * 256 + kidx);
        bl[n] = *(const bf16x8*)(Wtlo + (size_t)col * 256 + kidx);
      }
#pragma unroll
      for (int m = 0; m < 4; ++m) {
        int rl = wr * 64 + m * 16 + l15;
        int kb = (kk * 64 + lg * 16) ^ ((rl & 7) << 4);  // swizzled read
        bf16x8 ah = *(const bf16x8*)&As[0][rl * 64 + (kb >> 1)];
        bf16x8 al = *(const bf16x8*)&As[1][rl * 64 + (kb >> 1)];
#pragma unroll
        for (int n = 0; n < 4; ++n) {
          acc[m][n] = __builtin_amdgcn_mfma_f32_16x16x32_bf16(ah, bh[n], acc[m][n], 0, 0, 0);
          acc[m][n] = __builtin_amdgcn_mfma_f32_16x16x32_bf16(al, bh[n], acc[m][n], 0, 0, 0);
          acc[m][n] = __builtin_amdgcn_mfma_f32_16x16x32_bf16(ah, bl[n], acc[m][n], 0, 0, 0);
        }
      }
    }
  }

  // epilogue: bias, store, BN partial stats (exact fp32)
  __syncthreads();
  float* sred = (float*)&As[0][0];  // [s 128][s2 128]
  sred[tid] = 0.f;
  __syncthreads();
#pragma unroll
  for (int n = 0; n < 4; ++n) {
    int cb = wc * 64 + n * 16 + l15;
    int col = col0 + cb;
    float bv = bias[col];
    float s = 0.f, s2 = 0.f;
#pragma unroll
    for (int m = 0; m < 4; ++m) {
      int rbase = row0 + wr * 64 + m * 16 + lg * 4;
      f32x4 v = acc[m][n];
#pragma unroll
      for (int j = 0; j < 4; ++j) {
        int r = rbase + j;
        if (r < M) {
          float val = v[j] + bv;
          Y[(size_t)r * 256 + col] = val;
          s += val; s2 += val * val;
        }
      }
    }
    atomicAdd(&sred[cb], s);
    atomicAdd(&sred[128 + cb], s2);
  }
  __syncthreads();
  if (tid < 128) {
    atomicAdd(&stats[col0 + tid], sred[tid]);
    atomicAdd(&stats[256 + col0 + tid], sred[128 + tid]);
  }
}

// ---------------- BN scale/shift ----------------
__global__ void k_scaleshift(const float* __restrict__ stats, const float* __restrict__ g,
                             const float* __restrict__ be, float* __restrict__ ss, int N) {
  int c = threadIdx.x;
  float inv = 1.0f / (float)N;
  float mean = stats[c] * inv;
  float var = stats[256 + c] * inv - mean * mean;
  var = fmaxf(var, 0.f);
  float sc = g[c] * rsqrtf(var + 1e-5f);
  ss[c] = sc;
  ss[256 + c] = be[c] - mean * sc;
}

// ---------------- pooling with fused BN+ReLU ----------------
__global__ __launch_bounds__(256) void k_pool(const float* __restrict__ Y,
    const float* __restrict__ ss, const int* __restrict__ gstart,
    float* __restrict__ pooled) {
  int g = blockIdx.x, c = threadIdx.x;
  float sc = ss[c], sh = ss[256 + c];
  int n0 = gstart[g], n1 = gstart[g + 1];
  float s = 0.f, m = 0.f;
  for (int n = n0; n < n1; ++n) {
    float v = fmaxf(fmaf(Y[(size_t)n * 256 + c], sc, sh), 0.f);
    s += v; m = fmaxf(m, v);
  }
  float cnt = (float)(n1 - n0);
  pooled[g * 512 + c] = s / fmaxf(cnt, 1.0f);
  pooled[g * 512 + 256 + c] = m;
}

// ---------------- MLP + heads ----------------
__global__ __launch_bounds__(256) void k_mlp1(const float* __restrict__ P,
    const float* __restrict__ W, const float* __restrict__ b, float* __restrict__ O) {
  __shared__ float Ps[8 * 512];
  int tid = threadIdx.x;
  int g0 = blockIdx.x * 8;
  for (int j = 0; j < 16; ++j) Ps[tid + j * 256] = P[g0 * 512 + tid + j * 256];
  __syncthreads();
  float acc[8];
  float bb = b[tid];
#pragma unroll
  for (int gi = 0; gi < 8; ++gi) acc[gi] = bb;
  for (int k = 0; k < 512; ++k) {
    float w = W[k * 256 + tid];
#pragma unroll
    for (int gi = 0; gi < 8; ++gi) acc[gi] += Ps[gi * 512 + k] * w;
  }
  for (int gi = 0; gi < 8; ++gi)
    O[(g0 + gi) * 256 + tid] = fmaxf(acc[gi], 0.f);
}

__global__ __launch_bounds__(128) void k_mlp2(const float* __restrict__ S,
    const float* __restrict__ W, const float* __restrict__ b, float* __restrict__ O) {
  __shared__ float Ss[16 * 256];
  int tid = threadIdx.x;
  int g0 = blockIdx.x * 16;
  for (int j = 0; j < 32; ++j) Ss[tid + j * 128] = S[g0 * 256 + tid + j * 128];
  __syncthreads();
  float acc[16];
  float bb = b[tid];
#pragma unroll
  for (int gi = 0; gi < 16; ++gi) acc[gi] = bb;
  for (int k = 0; k < 256; ++k) {
    float w = W[k * 128 + tid];
#pragma unroll
    for (int gi = 0; gi < 16; ++gi) acc[gi] += Ss[gi * 256 + k] * w;
  }
  for (int gi = 0; gi < 16; ++gi)
    O[(g0 + gi) * 128 + tid] = fmaxf(acc[gi], 0.f);
}

__global__ __launch_bounds__(128) void k_heads(const float* __restrict__ S,
    const float* __restrict__ hW1, const float* __restrict__ hb1,
    const float* __restrict__ hW2, const float* __restrict__ hb2,
    float* __restrict__ out) {
  __shared__ float ssm[128];
  __shared__ float t1[96];
  int g = blockIdx.x, tid = threadIdx.x;
  ssm[tid] = S[g * 128 + tid];
  __syncthreads();
  if (tid < 96) {
    int t = tid >> 5, o = tid & 31;
    float acc = hb1[t * 32 + o];
    for (int k = 0; k < 128; ++k) acc += ssm[k] * hW1[t * 4096 + k * 32 + o];
    t1[tid] = fmaxf(acc, 0.f);
  }
  __syncthreads();
  if (tid < 3) {
    float acc = hb2[tid];
    for (int o = 0; o < 32; ++o) acc += t1[tid * 32 + o] * hW2[tid * 32 + o];
    out[tid * NGRAPH + g] = acc;
  }
}

// ---------------- host launcher ----------------
extern "C" void kernel_launch(void* const* d_in, const int* in_sizes, int n_in,
                              void* d_out, int out_size, void* d_ws, size_t ws_size,
                              hipStream_t stream) {
  const float* x   = (const float*)d_in[0];
  const int* ei    = (const int*)d_in[1];
  const int* batch = (const int*)d_in[2];
  const float* W1 = (const float*)d_in[3];  const float* b1 = (const float*)d_in[4];
  const float* W2 = (const float*)d_in[5];  const float* b2 = (const float*)d_in[6];
  const float* W3 = (const float*)d_in[7];  const float* b3 = (const float*)d_in[8];
  const float* W4 = (const float*)d_in[9];  const float* b4 = (const float*)d_in[10];
  const float* g1 = (const float*)d_in[11]; const float* be1 = (const float*)d_in[12];
  const float* g2 = (const float*)d_in[13]; const float* be2 = (const float*)d_in[14];
  const float* g3 = (const float*)d_in[15]; const float* be3 = (const float*)d_in[16];
  const float* g4 = (const float*)d_in[17]; const float* be4 = (const float*)d_in[18];
  const float* sW1 = (const float*)d_in[19]; const float* sb1 = (const float*)d_in[20];
  const float* sW2 = (const float*)d_in[21]; const float* sb2 = (const float*)d_in[22];
  const float* hW1 = (const float*)d_in[23]; const float* hb1 = (const float*)d_in[24];
  const float* hW2 = (const float*)d_in[25]; const float* hb2 = (const float*)d_in[26];

  const int N = in_sizes[0] / 8;
  const int E = in_sizes[1] / 2;
  const int Npad = (N + 127) & ~127;
  const int* srcp = ei;
  const int* dstp = ei + E;

  char* base = (char*)d_ws;
  size_t off = 0;
  auto alloc = [&](size_t bytes) -> void* {
    void* p = base + off;
    off += (bytes + 255) & ~(size_t)255;
    return p;
  };
  float* Ybuf = (float*)alloc((size_t)Npad * 256 * 4);
  unsigned short* Ahi = (unsigned short*)alloc((size_t)Npad * 256 * 2);
  unsigned short* Alo = (unsigned short*)alloc((size_t)Npad * 256 * 2);
  float* dis  = (float*)alloc((size_t)N * 4);
  int* cnt    = (int*)alloc((size_t)N * 4);
  int* rs     = (int*)alloc((size_t)(N + 1) * 4);
  int* cursor = (int*)alloc((size_t)N * 4);
  int* es     = (int*)alloc((size_t)E * 4);
  int* bsum   = (int*)alloc(1024 * 4);
  int* bsumx  = (int*)alloc(1032 * 4);
  float* xa8  = (float*)alloc((size_t)N * 8 * 4);
  float* statsAll = (float*)alloc(2048 * 4);
  float* ssAll    = (float*)alloc(2048 * 4);
  unsigned short* Wthi = (unsigned short*)alloc(3 * 256 * 256 * 2);
  unsigned short* Wtlo = (unsigned short*)alloc(3 * 256 * 256 * 2);
  int* cntg    = (int*)alloc(2048 * 4);
  int* gstart  = (int*)alloc(2049 * 4);
  float* pooled = (float*)alloc((size_t)2048 * 512 * 4);
  float* s1b    = (float*)alloc((size_t)2048 * 256 * 4);
  float* s2b    = (float*)alloc((size_t)2048 * 128 * 4);
  (void)ws_size; (void)n_in; (void)out_size;

  int nb = (N + TPB - 1) / TPB;
  int eb = (E + TPB - 1) / TPB;
  int nblocks1 = (N + 1023) / 1024;

  k_init<<<nb, TPB, 0, stream>>>(dis, cnt, cntg, statsAll, N);
  k_deg_hist<<<eb, TPB, 0, stream>>>(dstp, dis, cnt, E);
  k_hist_batch<<<nb, TPB, 0, stream>>>(batch, cntg, N);
  k_rsqrt<<<nb, TPB, 0, stream>>>(dis, N);
  k_scan1<<<nblocks1, 256, 0, stream>>>(cnt, rs, bsum, N);
  k_scan_small<<<1, 256, 0, stream>>>(bsum, bsumx, nblocks1);
  k_scan3<<<nb, TPB, 0, stream>>>(rs, bsumx, cursor, N, E);
  k_scatter<<<eb, TPB, 0, stream>>>(srcp, dstp, cursor, es, E);
  k_scan_small<<<1, 256, 0, stream>>>(cntg, gstart, NGRAPH);

  // weight prep (layers 2..4)
  k_wprep<<<256, 256, 0, stream>>>(W2, Wthi + 0 * 65536, Wtlo + 0 * 65536);
  k_wprep<<<256, 256, 0, stream>>>(W3, Wthi + 1 * 65536, Wtlo + 1 * 65536);
  k_wprep<<<256, 256, 0, stream>>>(W4, Wthi + 2 * 65536, Wtlo + 2 * 65536);

  // ---- layer 1: aggregate on D=8, project (fp32), fused stats ----
  k_agg8<<<(N * 8 + TPB - 1) / TPB, TPB, 0, stream>>>(x, dis, rs, es, xa8, N);
  k_gemm8<<<(N + 63) / 64, 256, 0, stream>>>(xa8, W1, b1, Ybuf, statsAll, N);
  k_scaleshift<<<1, 256, 0, stream>>>(statsAll, g1, be1, ssAll, N);

  // ---- layers 2..4 ----
  const float* bs_[3] = {b2, b3, b4};
  const float* gs[3]  = {g2, g3, g4};
  const float* bes[3] = {be2, be3, be4};
  dim3 gg((Npad) / 128, 2);
  for (int L = 0; L < 3; ++L) {
    k_agg_bn<<<(N + 3) / 4, 256, 0, stream>>>(Ybuf, ssAll + L * 512, dis, rs, es,
                                              Ahi, Alo, N);
    k_gemm_mfma<<<gg, 256, 0, stream>>>(Ahi, Alo, Wthi + L * 65536, Wtlo + L * 65536,
                                        bs_[L], Ybuf, statsAll + (L + 1) * 512, N);
    k_scaleshift<<<1, 256, 0, stream>>>(statsAll + (L + 1) * 512, gs[L], bes[L],
                                        ssAll + (L + 1) * 512, N);
  }

  // ---- pooling (fused BN+ReLU of layer 4) + MLP + heads ----
  k_pool<<<NGRAPH, 256, 0, stream>>>(Ybuf, ssAll + 3 * 512, gstart, pooled);
  k_mlp1<<<NGRAPH / 8, 256, 0, stream>>>(pooled, sW1, sb1, s1b);
  k_mlp2<<<NGRAPH / 16, 128, 0, stream>>>(s1b, sW2, sb2, s2b);
  k_heads<<<NGRAPH, 128, 0, stream>>>(s2b, hW1, hb1, hW2, hb2, (float*)d_out);
}

// Round 6
// 769.660 us; speedup vs baseline: 1.8117x; 1.1079x over previous
//
#include <hip/hip_runtime.h>
#include <math.h>

#define TPB 256
#define NGRAPH 2048

typedef __attribute__((ext_vector_type(8))) short bf16x8;
typedef __attribute__((ext_vector_type(4))) float f32x4;

__device__ __forceinline__ unsigned short f2bf(float f) {
  unsigned u = __float_as_uint(f);
  unsigned r = (u + 0x7FFF + ((u >> 16) & 1)) >> 16;
  return (unsigned short)r;
}
__device__ __forceinline__ float bf2f(unsigned short h) {
  return __uint_as_float(((unsigned)h) << 16);
}

#define GLOAD_LDS16(G, L) \
  __builtin_amdgcn_global_load_lds((const __attribute__((address_space(1))) unsigned int*)(G), \
                                   (__attribute__((address_space(3))) unsigned int*)(L), 16, 0, 0)

// ---------------- init / degree / histograms ----------------
__global__ void k_init(float* __restrict__ deg, int* __restrict__ cnt,
                       int* __restrict__ cntg, float* __restrict__ statsAll, int N) {
  int i = blockIdx.x * TPB + threadIdx.x;
  if (i < N) { deg[i] = 1.0f; cnt[i] = 0; }
  if (i < NGRAPH) cntg[i] = 0;
  if (i < 2048) statsAll[i] = 0.f;
}

__global__ void k_deg_hist(const int* __restrict__ dst, float* __restrict__ deg,
                           int* __restrict__ cnt, int E) {
  int e = blockIdx.x * TPB + threadIdx.x;
  if (e < E) {
    int d = dst[e];
    atomicAdd(&deg[d], 1.0f);
    atomicAdd(&cnt[d], 1);
  }
}

__global__ void k_hist_batch(const int* __restrict__ batch, int* __restrict__ cntg, int N) {
  int i = blockIdx.x * TPB + threadIdx.x;
  if (i < N) atomicAdd(&cntg[batch[i]], 1);
}

__global__ void k_rsqrt(float* __restrict__ d, int N) {
  int i = blockIdx.x * TPB + threadIdx.x;
  if (i < N) d[i] = rsqrtf(d[i]);
}

// ---------------- scans ----------------
__global__ void k_scan1(const int* __restrict__ in, int* __restrict__ out,
                        int* __restrict__ bsum, int n) {
  __shared__ int ts[256];
  int tid = threadIdx.x;
  int base = blockIdx.x * 1024 + tid * 4;
  int v0 = (base + 0 < n) ? in[base + 0] : 0;
  int v1 = (base + 1 < n) ? in[base + 1] : 0;
  int v2 = (base + 2 < n) ? in[base + 2] : 0;
  int v3 = (base + 3 < n) ? in[base + 3] : 0;
  int s = v0 + v1 + v2 + v3;
  int run = s;
  ts[tid] = run; __syncthreads();
  for (int off = 1; off < 256; off <<= 1) {
    int add = (tid >= off) ? ts[tid - off] : 0;
    __syncthreads();
    run += add; ts[tid] = run; __syncthreads();
  }
  int acc = run - s;
  if (base + 0 < n) out[base + 0] = acc; acc += v0;
  if (base + 1 < n) out[base + 1] = acc; acc += v1;
  if (base + 2 < n) out[base + 2] = acc; acc += v2;
  if (base + 3 < n) out[base + 3] = acc;
  if (tid == 255) bsum[blockIdx.x] = run;
}

__global__ void k_scan_small(const int* __restrict__ in, int* __restrict__ dst, int n) {
  __shared__ int ts[256];
  int tid = threadIdx.x;
  int chunk = (n + 255) >> 8;
  int start = tid * chunk;
  int s = 0;
  for (int j = 0; j < chunk; ++j) { int idx = start + j; if (idx < n) s += in[idx]; }
  int run = s;
  ts[tid] = run; __syncthreads();
  for (int off = 1; off < 256; off <<= 1) {
    int add = (tid >= off) ? ts[tid - off] : 0;
    __syncthreads();
    run += add; ts[tid] = run; __syncthreads();
  }
  int acc = run - s;
  for (int j = 0; j < chunk; ++j) {
    int idx = start + j;
    if (idx < n) { dst[idx] = acc; acc += in[idx]; }
  }
  if (tid == 255) dst[n] = run;
}

__global__ void k_scan3(int* __restrict__ rs, const int* __restrict__ bsumx,
                        int* __restrict__ cursor, int n, int total) {
  int i = blockIdx.x * TPB + threadIdx.x;
  if (i < n) {
    int v = rs[i] + bsumx[i >> 10];
    rs[i] = v; cursor[i] = v;
  }
  if (i == 0) rs[n] = total;
}

__global__ void k_scatter(const int* __restrict__ src, const int* __restrict__ dst,
                          int* __restrict__ cursor, int* __restrict__ es, int E) {
  int e = blockIdx.x * TPB + threadIdx.x;
  if (e < E) {
    int d = dst[e];
    int p = atomicAdd(&cursor[d], 1);
    es[p] = src[e];
  }
}

// ---------------- weight prep: transpose + hi/lo split ----------------
__global__ __launch_bounds__(256) void k_wprep(const float* __restrict__ W,
    unsigned short* __restrict__ Wthi, unsigned short* __restrict__ Wtlo) {
  int c = blockIdx.x, k = threadIdx.x;
  float w = W[k * 256 + c];
  unsigned short h = f2bf(w);
  Wthi[c * 256 + k] = h;
  Wtlo[c * 256 + k] = f2bf(w - bf2f(h));
}

// ---------------- layer-1 aggregation on D=8 (fp32) ----------------
__global__ void k_agg8(const float* __restrict__ x, const float* __restrict__ dis,
                       const int* __restrict__ rs, const int* __restrict__ es,
                       float* __restrict__ xa8, int N) {
  int t = blockIdx.x * TPB + threadIdx.x;
  int n = t >> 3, c = t & 7;
  if (n >= N) return;
  int e0 = rs[n], e1 = rs[n + 1];
  float acc = 0.f;
  for (int e = e0; e < e1; ++e) {
    int s = es[e];
    acc += dis[s] * x[s * 8 + c];
  }
  float dn = dis[n];
  xa8[n * 8 + c] = dn * acc + dn * dn * x[n * 8 + c];
}

// y[N,256] = xa8[N,8] @ W[8,256] + b, fused BN stats
__global__ __launch_bounds__(256) void k_gemm8(const float* __restrict__ A,
    const float* __restrict__ W, const float* __restrict__ b,
    float* __restrict__ Y, float* __restrict__ stats, int N) {
  __shared__ float Ws[8 * 256];
  __shared__ float bs[256];
  __shared__ float rows[64 * 8];
  int tid = threadIdx.x;
  int row0 = blockIdx.x * 64;
  for (int j = 0; j < 8; ++j) Ws[tid + j * 256] = W[tid + j * 256];
  bs[tid] = b[tid];
  int lim = N * 8;
  int o0 = row0 * 8 + tid, o1 = o0 + 256;
  rows[tid] = (o0 < lim) ? A[o0] : 0.f;
  rows[tid + 256] = (o1 < lim) ? A[o1] : 0.f;
  __syncthreads();
  float s = 0.f, s2 = 0.f;
  for (int r = 0; r < 64; ++r) {
    int row = row0 + r;
    if (row >= N) break;
    float acc = bs[tid];
#pragma unroll
    for (int k = 0; k < 8; ++k) acc += rows[r * 8 + k] * Ws[k * 256 + tid];
    Y[(size_t)row * 256 + tid] = acc;
    s += acc; s2 += acc * acc;
  }
  atomicAdd(&stats[tid], s);
  atomicAdd(&stats[256 + tid], s2);
}

// ---------------- fused BN+ReLU aggregation, wave per node ----------------
// writes single bf16 plane (W-side compensation in the GEMM)
__global__ __launch_bounds__(256) void k_agg_bn(const float* __restrict__ Y,
    const float* __restrict__ ss, const float* __restrict__ dis,
    const int* __restrict__ rs, const int* __restrict__ es,
    unsigned short* __restrict__ Ahi, int N) {
  int lane = threadIdx.x & 63;
  int n = __builtin_amdgcn_readfirstlane(blockIdx.x * 4 + (threadIdx.x >> 6));
  if (n >= N) return;
  int c = lane * 4;
  float4 sc = *(const float4*)&ss[c];
  float4 sh = *(const float4*)&ss[256 + c];
  int e0 = rs[n], e1 = rs[n + 1];
  float4 a = make_float4(0.f, 0.f, 0.f, 0.f);
  for (int e = e0; e < e1; ++e) {
    int s = es[e];
    float d = dis[s];
    float4 y = *(const float4*)&Y[(size_t)s * 256 + c];
    a.x += d * fmaxf(fmaf(y.x, sc.x, sh.x), 0.f);
    a.y += d * fmaxf(fmaf(y.y, sc.y, sh.y), 0.f);
    a.z += d * fmaxf(fmaf(y.z, sc.z, sh.z), 0.f);
    a.w += d * fmaxf(fmaf(y.w, sc.w, sh.w), 0.f);
  }
  float dn = dis[n];
  float dn2 = dn * dn;
  float4 y = *(const float4*)&Y[(size_t)n * 256 + c];
  float4 r;
  r.x = dn * a.x + dn2 * fmaxf(fmaf(y.x, sc.x, sh.x), 0.f);
  r.y = dn * a.y + dn2 * fmaxf(fmaf(y.y, sc.y, sh.y), 0.f);
  r.z = dn * a.z + dn2 * fmaxf(fmaf(y.z, sc.z, sh.z), 0.f);
  r.w = dn * a.w + dn2 * fmaxf(fmaf(y.w, sc.w, sh.w), 0.f);
  ushort4 h;
  h.x = f2bf(r.x); h.y = f2bf(r.y); h.z = f2bf(r.z); h.w = f2bf(r.w);
  *(ushort4*)&Ahi[(size_t)n * 256 + c] = h;
}

// ---------------- MFMA GEMM: Y[M,256] = A[M,256] @ (Wh+Wl)[256,256] + b
// 2-pass W-compensated bf16. 2-phase pipelined K-loop, dbuf LDS, 1 barrier/step.
// block: 256 thr = 4 waves (2x2), tile 128x128, BK=64, K=256
__global__ __launch_bounds__(256) void k_gemm_mfma(
    const unsigned short* __restrict__ A,
    const unsigned short* __restrict__ Wthi, const unsigned short* __restrict__ Wtlo,
    const float* __restrict__ bias, float* __restrict__ Y,
    float* __restrict__ stats, int M) {
  __shared__ unsigned short As[2][128 * 64];  // dbuf, xor-swizzled 16B chunks
  const int tid = threadIdx.x;
  const int lane = tid & 63;
  const int wid = tid >> 6;
  const int wr = wid >> 1, wc = wid & 1;
  const int l15 = lane & 15, lg = lane >> 4;
  const int row0 = blockIdx.x * 128;
  const int col0 = blockIdx.y * 128;

  f32x4 acc[4][4] = {};

  // stage one 128x64 bf16 K-tile: 4 x gload_lds16 per thread
  // linear LDS dest + inverse-swizzled global source (rule #21)
#define STAGE(buf, k0)                                                        \
  {                                                                           \
    _Pragma("unroll")                                                         \
    for (int it = 0; it < 4; ++it) {                                          \
      int L = it * 4096 + tid * 16;                                           \
      int row = L >> 7;                                                       \
      int kb = L & 127;                                                       \
      int skb = kb ^ ((row & 7) << 4);                                        \
      GLOAD_LDS16(A + (size_t)(row0 + row) * 256 + (k0) + (skb >> 1),         \
                  &As[buf][L >> 1]);                                          \
    }                                                                         \
  }

  STAGE(0, 0);
  __syncthreads();
  int cur = 0;
#pragma unroll
  for (int t = 0; t < 4; ++t) {
    if (t < 3) STAGE(cur ^ 1, (t + 1) * 64);  // prefetch next tile under compute
    const int k0 = t * 64;
    // hoist all B-fragment loads (L2-hot 256KB) ahead of the MFMA cluster
    bf16x8 bh[2][4], bl[2][4];
#pragma unroll
    for (int kk = 0; kk < 2; ++kk)
#pragma unroll
      for (int n = 0; n < 4; ++n) {
        int col = col0 + wc * 64 + n * 16 + l15;
        int kidx = k0 + kk * 32 + lg * 8;
        bh[kk][n] = *(const bf16x8*)(Wthi + (size_t)col * 256 + kidx);
        bl[kk][n] = *(const bf16x8*)(Wtlo + (size_t)col * 256 + kidx);
      }
#pragma unroll
    for (int kk = 0; kk < 2; ++kk) {
#pragma unroll
      for (int m = 0; m < 4; ++m) {
        int rl = wr * 64 + m * 16 + l15;
        int kb = (kk * 64 + lg * 16) ^ ((rl & 7) << 4);  // swizzled read
        bf16x8 ah = *(const bf16x8*)&As[cur][rl * 64 + (kb >> 1)];
#pragma unroll
        for (int n = 0; n < 4; ++n) {
          acc[m][n] = __builtin_amdgcn_mfma_f32_16x16x32_bf16(ah, bh[kk][n], acc[m][n], 0, 0, 0);
          acc[m][n] = __builtin_amdgcn_mfma_f32_16x16x32_bf16(ah, bl[kk][n], acc[m][n], 0, 0, 0);
        }
      }
    }
    __syncthreads();  // drains prefetch vmcnt + synchronizes buffer reuse
    cur ^= 1;
  }

  // epilogue: bias, store, BN partial stats (exact fp32)
  float* sred = (float*)&As[0][0];
  sred[tid] = 0.f;
  __syncthreads();
#pragma unroll
  for (int n = 0; n < 4; ++n) {
    int cb = wc * 64 + n * 16 + l15;
    int col = col0 + cb;
    float bv = bias[col];
    float s = 0.f, s2 = 0.f;
#pragma unroll
    for (int m = 0; m < 4; ++m) {
      int rbase = row0 + wr * 64 + m * 16 + lg * 4;
      f32x4 v = acc[m][n];
#pragma unroll
      for (int j = 0; j < 4; ++j) {
        int r = rbase + j;
        if (r < M) {
          float val = v[j] + bv;
          Y[(size_t)r * 256 + col] = val;
          s += val; s2 += val * val;
        }
      }
    }
    atomicAdd(&sred[cb], s);
    atomicAdd(&sred[128 + cb], s2);
  }
  __syncthreads();
  if (tid < 128) {
    atomicAdd(&stats[col0 + tid], sred[tid]);
    atomicAdd(&stats[256 + col0 + tid], sred[128 + tid]);
  }
}

// ---------------- BN scale/shift ----------------
__global__ void k_scaleshift(const float* __restrict__ stats, const float* __restrict__ g,
                             const float* __restrict__ be, float* __restrict__ ss, int N) {
  int c = threadIdx.x;
  float inv = 1.0f / (float)N;
  float mean = stats[c] * inv;
  float var = stats[256 + c] * inv - mean * mean;
  var = fmaxf(var, 0.f);
  float sc = g[c] * rsqrtf(var + 1e-5f);
  ss[c] = sc;
  ss[256 + c] = be[c] - mean * sc;
}

// ---------------- pooling with fused BN+ReLU ----------------
__global__ __launch_bounds__(256) void k_pool(const float* __restrict__ Y,
    const float* __restrict__ ss, const int* __restrict__ gstart,
    float* __restrict__ pooled) {
  int g = blockIdx.x, c = threadIdx.x;
  float sc = ss[c], sh = ss[256 + c];
  int n0 = gstart[g], n1 = gstart[g + 1];
  float s = 0.f, m = 0.f;
  for (int n = n0; n < n1; ++n) {
    float v = fmaxf(fmaf(Y[(size_t)n * 256 + c], sc, sh), 0.f);
    s += v; m = fmaxf(m, v);
  }
  float cnt = (float)(n1 - n0);
  pooled[g * 512 + c] = s / fmaxf(cnt, 1.0f);
  pooled[g * 512 + 256 + c] = m;
}

// ---------------- MLP + heads ----------------
__global__ __launch_bounds__(256) void k_mlp1(const float* __restrict__ P,
    const float* __restrict__ W, const float* __restrict__ b, float* __restrict__ O) {
  __shared__ float Ps[8 * 512];
  int tid = threadIdx.x;
  int g0 = blockIdx.x * 8;
  for (int j = 0; j < 16; ++j) Ps[tid + j * 256] = P[g0 * 512 + tid + j * 256];
  __syncthreads();
  float acc[8];
  float bb = b[tid];
#pragma unroll
  for (int gi = 0; gi < 8; ++gi) acc[gi] = bb;
  for (int k = 0; k < 512; ++k) {
    float w = W[k * 256 + tid];
#pragma unroll
    for (int gi = 0; gi < 8; ++gi) acc[gi] += Ps[gi * 512 + k] * w;
  }
  for (int gi = 0; gi < 8; ++gi)
    O[(g0 + gi) * 256 + tid] = fmaxf(acc[gi], 0.f);
}

__global__ __launch_bounds__(128) void k_mlp2(const float* __restrict__ S,
    const float* __restrict__ W, const float* __restrict__ b, float* __restrict__ O) {
  __shared__ float Ss[16 * 256];
  int tid = threadIdx.x;
  int g0 = blockIdx.x * 16;
  for (int j = 0; j < 32; ++j) Ss[tid + j * 128] = S[g0 * 256 + tid + j * 128];
  __syncthreads();
  float acc[16];
  float bb = b[tid];
#pragma unroll
  for (int gi = 0; gi < 16; ++gi) acc[gi] = bb;
  for (int k = 0; k < 256; ++k) {
    float w = W[k * 128 + tid];
#pragma unroll
    for (int gi = 0; gi < 16; ++gi) acc[gi] += Ss[gi * 256 + k] * w;
  }
  for (int gi = 0; gi < 16; ++gi)
    O[(g0 + gi) * 128 + tid] = fmaxf(acc[gi], 0.f);
}

__global__ __launch_bounds__(128) void k_heads(const float* __restrict__ S,
    const float* __restrict__ hW1, const float* __restrict__ hb1,
    const float* __restrict__ hW2, const float* __restrict__ hb2,
    float* __restrict__ out) {
  __shared__ float ssm[128];
  __shared__ float t1[96];
  int g = blockIdx.x, tid = threadIdx.x;
  ssm[tid] = S[g * 128 + tid];
  __syncthreads();
  if (tid < 96) {
    int t = tid >> 5, o = tid & 31;
    float acc = hb1[t * 32 + o];
    for (int k = 0; k < 128; ++k) acc += ssm[k] * hW1[t * 4096 + k * 32 + o];
    t1[tid] = fmaxf(acc, 0.f);
  }
  __syncthreads();
  if (tid < 3) {
    float acc = hb2[tid];
    for (int o = 0; o < 32; ++o) acc += t1[tid * 32 + o] * hW2[tid * 32 + o];
    out[tid * NGRAPH + g] = acc;
  }
}

// ---------------- host launcher ----------------
extern "C" void kernel_launch(void* const* d_in, const int* in_sizes, int n_in,
                              void* d_out, int out_size, void* d_ws, size_t ws_size,
                              hipStream_t stream) {
  const float* x   = (const float*)d_in[0];
  const int* ei    = (const int*)d_in[1];
  const int* batch = (const int*)d_in[2];
  const float* W1 = (const float*)d_in[3];  const float* b1 = (const float*)d_in[4];
  const float* W2 = (const float*)d_in[5];  const float* b2 = (const float*)d_in[6];
  const float* W3 = (const float*)d_in[7];  const float* b3 = (const float*)d_in[8];
  const float* W4 = (const float*)d_in[9];  const float* b4 = (const float*)d_in[10];
  const float* g1 = (const float*)d_in[11]; const float* be1 = (const float*)d_in[12];
  const float* g2 = (const float*)d_in[13]; const float* be2 = (const float*)d_in[14];
  const float* g3 = (const float*)d_in[15]; const float* be3 = (const float*)d_in[16];
  const float* g4 = (const float*)d_in[17]; const float* be4 = (const float*)d_in[18];
  const float* sW1 = (const float*)d_in[19]; const float* sb1 = (const float*)d_in[20];
  const float* sW2 = (const float*)d_in[21]; const float* sb2 = (const float*)d_in[22];
  const float* hW1 = (const float*)d_in[23]; const float* hb1 = (const float*)d_in[24];
  const float* hW2 = (const float*)d_in[25]; const float* hb2 = (const float*)d_in[26];

  const int N = in_sizes[0] / 8;
  const int E = in_sizes[1] / 2;
  const int Npad = (N + 127) & ~127;
  const int* srcp = ei;
  const int* dstp = ei + E;

  char* base = (char*)d_ws;
  size_t off = 0;
  auto alloc = [&](size_t bytes) -> void* {
    void* p = base + off;
    off += (bytes + 255) & ~(size_t)255;
    return p;
  };
  float* Ybuf = (float*)alloc((size_t)Npad * 256 * 4);
  unsigned short* Ahi = (unsigned short*)alloc((size_t)Npad * 256 * 2);
  float* dis  = (float*)alloc((size_t)N * 4);
  int* cnt    = (int*)alloc((size_t)N * 4);
  int* rs     = (int*)alloc((size_t)(N + 1) * 4);
  int* cursor = (int*)alloc((size_t)N * 4);
  int* es     = (int*)alloc((size_t)E * 4);
  int* bsum   = (int*)alloc(1024 * 4);
  int* bsumx  = (int*)alloc(1032 * 4);
  float* xa8  = (float*)alloc((size_t)N * 8 * 4);
  float* statsAll = (float*)alloc(2048 * 4);
  float* ssAll    = (float*)alloc(2048 * 4);
  unsigned short* Wthi = (unsigned short*)alloc(3 * 256 * 256 * 2);
  unsigned short* Wtlo = (unsigned short*)alloc(3 * 256 * 256 * 2);
  int* cntg    = (int*)alloc(2048 * 4);
  int* gstart  = (int*)alloc(2049 * 4);
  float* pooled = (float*)alloc((size_t)2048 * 512 * 4);
  float* s1b    = (float*)alloc((size_t)2048 * 256 * 4);
  float* s2b    = (float*)alloc((size_t)2048 * 128 * 4);
  (void)ws_size; (void)n_in; (void)out_size;

  int nb = (N + TPB - 1) / TPB;
  int eb = (E + TPB - 1) / TPB;
  int nblocks1 = (N + 1023) / 1024;

  k_init<<<nb, TPB, 0, stream>>>(dis, cnt, cntg, statsAll, N);
  k_deg_hist<<<eb, TPB, 0, stream>>>(dstp, dis, cnt, E);
  k_hist_batch<<<nb, TPB, 0, stream>>>(batch, cntg, N);
  k_rsqrt<<<nb, TPB, 0, stream>>>(dis, N);
  k_scan1<<<nblocks1, 256, 0, stream>>>(cnt, rs, bsum, N);
  k_scan_small<<<1, 256, 0, stream>>>(bsum, bsumx, nblocks1);
  k_scan3<<<nb, TPB, 0, stream>>>(rs, bsumx, cursor, N, E);
  k_scatter<<<eb, TPB, 0, stream>>>(srcp, dstp, cursor, es, E);
  k_scan_small<<<1, 256, 0, stream>>>(cntg, gstart, NGRAPH);

  // weight prep (layers 2..4)
  k_wprep<<<256, 256, 0, stream>>>(W2, Wthi + 0 * 65536, Wtlo + 0 * 65536);
  k_wprep<<<256, 256, 0, stream>>>(W3, Wthi + 1 * 65536, Wtlo + 1 * 65536);
  k_wprep<<<256, 256, 0, stream>>>(W4, Wthi + 2 * 65536, Wtlo + 2 * 65536);

  // ---- layer 1: aggregate on D=8, project (fp32), fused stats ----
  k_agg8<<<(N * 8 + TPB - 1) / TPB, TPB, 0, stream>>>(x, dis, rs, es, xa8, N);
  k_gemm8<<<(N + 63) / 64, 256, 0, stream>>>(xa8, W1, b1, Ybuf, statsAll, N);
  k_scaleshift<<<1, 256, 0, stream>>>(statsAll, g1, be1, ssAll, N);

  // ---- layers 2..4 ----
  const float* bs_[3] = {b2, b3, b4};
  const float* gs[3]  = {g2, g3, g4};
  const float* bes[3] = {be2, be3, be4};
  dim3 gg((Npad) / 128, 2);
  for (int L = 0; L < 3; ++L) {
    k_agg_bn<<<(N + 3) / 4, 256, 0, stream>>>(Ybuf, ssAll + L * 512, dis, rs, es,
                                              Ahi, N);
    k_gemm_mfma<<<gg, 256, 0, stream>>>(Ahi, Wthi + L * 65536, Wtlo + L * 65536,
                                        bs_[L], Ybuf, statsAll + (L + 1) * 512, N);
    k_scaleshift<<<1, 256, 0, stream>>>(statsAll + (L + 1) * 512, gs[L], bes[L],
                                        ssAll + (L + 1) * 512, N);
  }

  // ---- pooling (fused BN+ReLU of layer 4) + MLP + heads ----
  k_pool<<<NGRAPH, 256, 0, stream>>>(Ybuf, ssAll + 3 * 512, gstart, pooled);
  k_mlp1<<<NGRAPH / 8, 256, 0, stream>>>(pooled, sW1, sb1, s1b);
  k_mlp2<<<NGRAPH / 16, 128, 0, stream>>>(s1b, sW2, sb2, s2b);
  k_heads<<<NGRAPH, 128, 0, stream>>>(s2b, hW1, hb1, hW2, hb2, (float*)d_out);
}

// Round 7
// 702.043 us; speedup vs baseline: 1.9861x; 1.0963x over previous
//
#include <hip/hip_runtime.h>
#include <math.h>

#define TPB 256
#define NGRAPH 2048

typedef __attribute__((ext_vector_type(8))) short bf16x8;
typedef __attribute__((ext_vector_type(4))) float f32x4;

__device__ __forceinline__ unsigned short f2bf(float f) {
  unsigned u = __float_as_uint(f);
  unsigned r = (u + 0x7FFF + ((u >> 16) & 1)) >> 16;
  return (unsigned short)r;
}
__device__ __forceinline__ float bf2f(unsigned short h) {
  return __uint_as_float(((unsigned)h) << 16);
}

#define GLOAD_LDS16(G, L) \
  __builtin_amdgcn_global_load_lds((const __attribute__((address_space(1))) unsigned int*)(G), \
                                   (__attribute__((address_space(3))) unsigned int*)(L), 16, 0, 0)

// ---------------- init / degree / histograms ----------------
__global__ void k_init(float* __restrict__ deg, int* __restrict__ cnt,
                       int* __restrict__ cntg, float* __restrict__ statsAll, int N) {
  int i = blockIdx.x * TPB + threadIdx.x;
  if (i < N) { deg[i] = 1.0f; cnt[i] = 0; }
  if (i < NGRAPH) cntg[i] = 0;
  if (i < 2048) statsAll[i] = 0.f;
}

__global__ void k_deg_hist(const int* __restrict__ dst, float* __restrict__ deg,
                           int* __restrict__ cnt, int E) {
  int e = blockIdx.x * TPB + threadIdx.x;
  if (e < E) {
    int d = dst[e];
    atomicAdd(&deg[d], 1.0f);
    atomicAdd(&cnt[d], 1);
  }
}

__global__ void k_hist_batch(const int* __restrict__ batch, int* __restrict__ cntg, int N) {
  int i = blockIdx.x * TPB + threadIdx.x;
  if (i < N) atomicAdd(&cntg[batch[i]], 1);
}

__global__ void k_rsqrt(float* __restrict__ d, int N) {
  int i = blockIdx.x * TPB + threadIdx.x;
  if (i < N) d[i] = rsqrtf(d[i]);
}

// ---------------- scans ----------------
__global__ void k_scan1(const int* __restrict__ in, int* __restrict__ out,
                        int* __restrict__ bsum, int n) {
  __shared__ int ts[256];
  int tid = threadIdx.x;
  int base = blockIdx.x * 1024 + tid * 4;
  int v0 = (base + 0 < n) ? in[base + 0] : 0;
  int v1 = (base + 1 < n) ? in[base + 1] : 0;
  int v2 = (base + 2 < n) ? in[base + 2] : 0;
  int v3 = (base + 3 < n) ? in[base + 3] : 0;
  int s = v0 + v1 + v2 + v3;
  int run = s;
  ts[tid] = run; __syncthreads();
  for (int off = 1; off < 256; off <<= 1) {
    int add = (tid >= off) ? ts[tid - off] : 0;
    __syncthreads();
    run += add; ts[tid] = run; __syncthreads();
  }
  int acc = run - s;
  if (base + 0 < n) out[base + 0] = acc; acc += v0;
  if (base + 1 < n) out[base + 1] = acc; acc += v1;
  if (base + 2 < n) out[base + 2] = acc; acc += v2;
  if (base + 3 < n) out[base + 3] = acc;
  if (tid == 255) bsum[blockIdx.x] = run;
}

__global__ void k_scan_small(const int* __restrict__ in, int* __restrict__ dst, int n) {
  __shared__ int ts[256];
  int tid = threadIdx.x;
  int chunk = (n + 255) >> 8;
  int start = tid * chunk;
  int s = 0;
  for (int j = 0; j < chunk; ++j) { int idx = start + j; if (idx < n) s += in[idx]; }
  int run = s;
  ts[tid] = run; __syncthreads();
  for (int off = 1; off < 256; off <<= 1) {
    int add = (tid >= off) ? ts[tid - off] : 0;
    __syncthreads();
    run += add; ts[tid] = run; __syncthreads();
  }
  int acc = run - s;
  for (int j = 0; j < chunk; ++j) {
    int idx = start + j;
    if (idx < n) { dst[idx] = acc; acc += in[idx]; }
  }
  if (tid == 255) dst[n] = run;
}

__global__ void k_scan3(int* __restrict__ rs, const int* __restrict__ bsumx,
                        int* __restrict__ cursor, int n, int total) {
  int i = blockIdx.x * TPB + threadIdx.x;
  if (i < n) {
    int v = rs[i] + bsumx[i >> 10];
    rs[i] = v; cursor[i] = v;
  }
  if (i == 0) rs[n] = total;
}

__global__ void k_scatter(const int* __restrict__ src, const int* __restrict__ dst,
                          int* __restrict__ cursor, int* __restrict__ es, int E) {
  int e = blockIdx.x * TPB + threadIdx.x;
  if (e < E) {
    int d = dst[e];
    int p = atomicAdd(&cursor[d], 1);
    es[p] = src[e];
  }
}

// ---------------- weight prep: transpose + hi/lo split ----------------
__global__ __launch_bounds__(256) void k_wprep(const float* __restrict__ W,
    unsigned short* __restrict__ Wthi, unsigned short* __restrict__ Wtlo) {
  int c = blockIdx.x, k = threadIdx.x;
  float w = W[k * 256 + c];
  unsigned short h = f2bf(w);
  Wthi[c * 256 + k] = h;
  Wtlo[c * 256 + k] = f2bf(w - bf2f(h));
}

// ---------------- layer-1 aggregation on D=8 (fp32) ----------------
__global__ void k_agg8(const float* __restrict__ x, const float* __restrict__ dis,
                       const int* __restrict__ rs, const int* __restrict__ es,
                       float* __restrict__ xa8, int N) {
  int t = blockIdx.x * TPB + threadIdx.x;
  int n = t >> 3, c = t & 7;
  if (n >= N) return;
  int e0 = rs[n], e1 = rs[n + 1];
  float acc = 0.f;
  for (int e = e0; e < e1; ++e) {
    int s = es[e];
    acc += dis[s] * x[s * 8 + c];
  }
  float dn = dis[n];
  xa8[n * 8 + c] = dn * acc + dn * dn * x[n * 8 + c];
}

// y[N,256] = xa8[N,8] @ W[8,256] + b, fused BN stats, bf16 output
__global__ __launch_bounds__(256) void k_gemm8(const float* __restrict__ A,
    const float* __restrict__ W, const float* __restrict__ b,
    unsigned short* __restrict__ Ybf, float* __restrict__ stats, int N) {
  __shared__ float Ws[8 * 256];
  __shared__ float bs[256];
  __shared__ float rows[64 * 8];
  int tid = threadIdx.x;
  int row0 = blockIdx.x * 64;
  for (int j = 0; j < 8; ++j) Ws[tid + j * 256] = W[tid + j * 256];
  bs[tid] = b[tid];
  int lim = N * 8;
  int o0 = row0 * 8 + tid, o1 = o0 + 256;
  rows[tid] = (o0 < lim) ? A[o0] : 0.f;
  rows[tid + 256] = (o1 < lim) ? A[o1] : 0.f;
  __syncthreads();
  float s = 0.f, s2 = 0.f;
  for (int r = 0; r < 64; ++r) {
    int row = row0 + r;
    if (row >= N) break;
    float acc = bs[tid];
#pragma unroll
    for (int k = 0; k < 8; ++k) acc += rows[r * 8 + k] * Ws[k * 256 + tid];
    Ybf[(size_t)row * 256 + tid] = f2bf(acc);
    s += acc; s2 += acc * acc;
  }
  atomicAdd(&stats[tid], s);
  atomicAdd(&stats[256 + tid], s2);
}

// ---------------- fused BN+ReLU aggregation, wave per node ----------------
// reads bf16 Y rows, writes single bf16 A plane
__global__ __launch_bounds__(256) void k_agg_bn(const unsigned short* __restrict__ Ybf,
    const float* __restrict__ ss, const float* __restrict__ dis,
    const int* __restrict__ rs, const int* __restrict__ es,
    unsigned short* __restrict__ Ahi, int N) {
  int lane = threadIdx.x & 63;
  int n = __builtin_amdgcn_readfirstlane(blockIdx.x * 4 + (threadIdx.x >> 6));
  if (n >= N) return;
  int c = lane * 4;
  float4 sc = *(const float4*)&ss[c];
  float4 sh = *(const float4*)&ss[256 + c];
  int e0 = rs[n], e1 = rs[n + 1];
  float4 a = make_float4(0.f, 0.f, 0.f, 0.f);
  for (int e = e0; e < e1; ++e) {
    int s = es[e];
    float d = dis[s];
    ushort4 yb = *(const ushort4*)&Ybf[(size_t)s * 256 + c];
    a.x += d * fmaxf(fmaf(bf2f(yb.x), sc.x, sh.x), 0.f);
    a.y += d * fmaxf(fmaf(bf2f(yb.y), sc.y, sh.y), 0.f);
    a.z += d * fmaxf(fmaf(bf2f(yb.z), sc.z, sh.z), 0.f);
    a.w += d * fmaxf(fmaf(bf2f(yb.w), sc.w, sh.w), 0.f);
  }
  float dn = dis[n];
  float dn2 = dn * dn;
  ushort4 yb = *(const ushort4*)&Ybf[(size_t)n * 256 + c];
  float4 r;
  r.x = dn * a.x + dn2 * fmaxf(fmaf(bf2f(yb.x), sc.x, sh.x), 0.f);
  r.y = dn * a.y + dn2 * fmaxf(fmaf(bf2f(yb.y), sc.y, sh.y), 0.f);
  r.z = dn * a.z + dn2 * fmaxf(fmaf(bf2f(yb.z), sc.z, sh.z), 0.f);
  r.w = dn * a.w + dn2 * fmaxf(fmaf(bf2f(yb.w), sc.w, sh.w), 0.f);
  ushort4 h;
  h.x = f2bf(r.x); h.y = f2bf(r.y); h.z = f2bf(r.z); h.w = f2bf(r.w);
  *(ushort4*)&Ahi[(size_t)n * 256 + c] = h;
}

// ---------------- MFMA GEMM: Y[M,256] = A[M,256] @ (Wh+Wl)[256,256] + b
// 2-pass W-compensated bf16. Counted-vmcnt pipelined K-loop (T4): the
// prefetch stays in flight across the barrier; each wave waits only the
// PREVIOUS tile's 4 gload_lds (oldest outstanding, FIFO per m135).
__global__ __launch_bounds__(256) void k_gemm_mfma(
    const unsigned short* __restrict__ A,
    const unsigned short* __restrict__ Wthi, const unsigned short* __restrict__ Wtlo,
    const float* __restrict__ bias, unsigned short* __restrict__ Ybf,
    float* __restrict__ stats, int M) {
  __shared__ unsigned short As[2][128 * 64];  // dbuf, xor-swizzled 16B chunks
  const int tid = threadIdx.x;
  const int lane = tid & 63;
  const int wid = tid >> 6;
  const int wr = wid >> 1, wc = wid & 1;
  const int l15 = lane & 15, lg = lane >> 4;
  const int row0 = blockIdx.x * 128;
  const int col0 = blockIdx.y * 128;

  f32x4 acc[4][4] = {};

  // stage one 128x64 bf16 K-tile: 4 x gload_lds16 per thread
  // linear LDS dest + inverse-swizzled global source (rule #21)
#define STAGE(buf, k0)                                                        \
  {                                                                           \
    _Pragma("unroll")                                                         \
    for (int it = 0; it < 4; ++it) {                                          \
      int L = it * 4096 + tid * 16;                                          \
      int row = L >> 7;                                                       \
      int kb = L & 127;                                                       \
      int skb = kb ^ ((row & 7) << 4);                                        \
      GLOAD_LDS16(A + (size_t)(row0 + row) * 256 + (k0) + (skb >> 1),         \
                  &As[buf][L >> 1]);                                          \
    }                                                                         \
  }

  STAGE(0, 0);
  int cur = 0;
#pragma unroll
  for (int t = 0; t < 4; ++t) {
    if (t < 3) {
      STAGE(cur ^ 1, (t + 1) * 64);  // prefetch next tile; stays in flight
      asm volatile("s_waitcnt vmcnt(4)" ::: "memory");  // wait tile t only
    } else {
      asm volatile("s_waitcnt vmcnt(0)" ::: "memory");
    }
    __builtin_amdgcn_s_barrier();  // all waves' tile-t loads landed
    const int k0 = t * 64;
    // hoist all B-fragment loads (L2-hot 256KB) ahead of the MFMA cluster
    bf16x8 bh[2][4], bl[2][4];
#pragma unroll
    for (int kk = 0; kk < 2; ++kk)
#pragma unroll
      for (int n = 0; n < 4; ++n) {
        int col = col0 + wc * 64 + n * 16 + l15;
        int kidx = k0 + kk * 32 + lg * 8;
        bh[kk][n] = *(const bf16x8*)(Wthi + (size_t)col * 256 + kidx);
        bl[kk][n] = *(const bf16x8*)(Wtlo + (size_t)col * 256 + kidx);
      }
#pragma unroll
    for (int kk = 0; kk < 2; ++kk) {
#pragma unroll
      for (int m = 0; m < 4; ++m) {
        int rl = wr * 64 + m * 16 + l15;
        int kb = (kk * 64 + lg * 16) ^ ((rl & 7) << 4);  // swizzled read
        bf16x8 ah = *(const bf16x8*)&As[cur][rl * 64 + (kb >> 1)];
#pragma unroll
        for (int n = 0; n < 4; ++n) {
          acc[m][n] = __builtin_amdgcn_mfma_f32_16x16x32_bf16(ah, bh[kk][n], acc[m][n], 0, 0, 0);
          acc[m][n] = __builtin_amdgcn_mfma_f32_16x16x32_bf16(ah, bl[kk][n], acc[m][n], 0, 0, 0);
        }
      }
    }
    // this wave's ds_reads of buf(cur) complete before signaling arrival,
    // so next iter's STAGE may safely overwrite buf(cur)
    asm volatile("s_waitcnt lgkmcnt(0)" ::: "memory");
    __builtin_amdgcn_s_barrier();
    cur ^= 1;
  }

  // epilogue: bias, bf16 store, BN partial stats (exact fp32)
  __syncthreads();
  float* sred = (float*)&As[0][0];
  sred[tid] = 0.f;
  __syncthreads();
#pragma unroll
  for (int n = 0; n < 4; ++n) {
    int cb = wc * 64 + n * 16 + l15;
    int col = col0 + cb;
    float bv = bias[col];
    float s = 0.f, s2 = 0.f;
#pragma unroll
    for (int m = 0; m < 4; ++m) {
      int rbase = row0 + wr * 64 + m * 16 + lg * 4;
      f32x4 v = acc[m][n];
#pragma unroll
      for (int j = 0; j < 4; ++j) {
        int r = rbase + j;
        if (r < M) {
          float val = v[j] + bv;
          Ybf[(size_t)r * 256 + col] = f2bf(val);
          s += val; s2 += val * val;
        }
      }
    }
    atomicAdd(&sred[cb], s);
    atomicAdd(&sred[128 + cb], s2);
  }
  __syncthreads();
  if (tid < 128) {
    atomicAdd(&stats[col0 + tid], sred[tid]);
    atomicAdd(&stats[256 + col0 + tid], sred[128 + tid]);
  }
}

// ---------------- BN scale/shift ----------------
__global__ void k_scaleshift(const float* __restrict__ stats, const float* __restrict__ g,
                             const float* __restrict__ be, float* __restrict__ ss, int N) {
  int c = threadIdx.x;
  float inv = 1.0f / (float)N;
  float mean = stats[c] * inv;
  float var = stats[256 + c] * inv - mean * mean;
  var = fmaxf(var, 0.f);
  float sc = g[c] * rsqrtf(var + 1e-5f);
  ss[c] = sc;
  ss[256 + c] = be[c] - mean * sc;
}

// ---------------- pooling with fused BN+ReLU (bf16 input) ----------------
__global__ __launch_bounds__(256) void k_pool(const unsigned short* __restrict__ Ybf,
    const float* __restrict__ ss, const int* __restrict__ gstart,
    float* __restrict__ pooled) {
  int g = blockIdx.x, c = threadIdx.x;
  float sc = ss[c], sh = ss[256 + c];
  int n0 = gstart[g], n1 = gstart[g + 1];
  float s = 0.f, m = 0.f;
  for (int n = n0; n < n1; ++n) {
    float v = fmaxf(fmaf(bf2f(Ybf[(size_t)n * 256 + c]), sc, sh), 0.f);
    s += v; m = fmaxf(m, v);
  }
  float cnt = (float)(n1 - n0);
  pooled[g * 512 + c] = s / fmaxf(cnt, 1.0f);
  pooled[g * 512 + 256 + c] = m;
}

// ---------------- MLP + heads ----------------
__global__ __launch_bounds__(256) void k_mlp1(const float* __restrict__ P,
    const float* __restrict__ W, const float* __restrict__ b, float* __restrict__ O) {
  __shared__ float Ps[8 * 512];
  int tid = threadIdx.x;
  int g0 = blockIdx.x * 8;
  for (int j = 0; j < 16; ++j) Ps[tid + j * 256] = P[g0 * 512 + tid + j * 256];
  __syncthreads();
  float acc[8];
  float bb = b[tid];
#pragma unroll
  for (int gi = 0; gi < 8; ++gi) acc[gi] = bb;
  for (int k = 0; k < 512; ++k) {
    float w = W[k * 256 + tid];
#pragma unroll
    for (int gi = 0; gi < 8; ++gi) acc[gi] += Ps[gi * 512 + k] * w;
  }
  for (int gi = 0; gi < 8; ++gi)
    O[(g0 + gi) * 256 + tid] = fmaxf(acc[gi], 0.f);
}

__global__ __launch_bounds__(128) void k_mlp2(const float* __restrict__ S,
    const float* __restrict__ W, const float* __restrict__ b, float* __restrict__ O) {
  __shared__ float Ss[16 * 256];
  int tid = threadIdx.x;
  int g0 = blockIdx.x * 16;
  for (int j = 0; j < 32; ++j) Ss[tid + j * 128] = S[g0 * 256 + tid + j * 128];
  __syncthreads();
  float acc[16];
  float bb = b[tid];
#pragma unroll
  for (int gi = 0; gi < 16; ++gi) acc[gi] = bb;
  for (int k = 0; k < 256; ++k) {
    float w = W[k * 128 + tid];
#pragma unroll
    for (int gi = 0; gi < 16; ++gi) acc[gi] += Ss[gi * 256 + k] * w;
  }
  for (int gi = 0; gi < 16; ++gi)
    O[(g0 + gi) * 128 + tid] = fmaxf(acc[gi], 0.f);
}

__global__ __launch_bounds__(128) void k_heads(const float* __restrict__ S,
    const float* __restrict__ hW1, const float* __restrict__ hb1,
    const float* __restrict__ hW2, const float* __restrict__ hb2,
    float* __restrict__ out) {
  __shared__ float ssm[128];
  __shared__ float t1[96];
  int g = blockIdx.x, tid = threadIdx.x;
  ssm[tid] = S[g * 128 + tid];
  __syncthreads();
  if (tid < 96) {
    int t = tid >> 5, o = tid & 31;
    float acc = hb1[t * 32 + o];
    for (int k = 0; k < 128; ++k) acc += ssm[k] * hW1[t * 4096 + k * 32 + o];
    t1[tid] = fmaxf(acc, 0.f);
  }
  __syncthreads();
  if (tid < 3) {
    float acc = hb2[tid];
    for (int o = 0; o < 32; ++o) acc += t1[tid * 32 + o] * hW2[tid * 32 + o];
    out[tid * NGRAPH + g] = acc;
  }
}

// ---------------- host launcher ----------------
extern "C" void kernel_launch(void* const* d_in, const int* in_sizes, int n_in,
                              void* d_out, int out_size, void* d_ws, size_t ws_size,
                              hipStream_t stream) {
  const float* x   = (const float*)d_in[0];
  const int* ei    = (const int*)d_in[1];
  const int* batch = (const int*)d_in[2];
  const float* W1 = (const float*)d_in[3];  const float* b1 = (const float*)d_in[4];
  const float* W2 = (const float*)d_in[5];  const float* b2 = (const float*)d_in[6];
  const float* W3 = (const float*)d_in[7];  const float* b3 = (const float*)d_in[8];
  const float* W4 = (const float*)d_in[9];  const float* b4 = (const float*)d_in[10];
  const float* g1 = (const float*)d_in[11]; const float* be1 = (const float*)d_in[12];
  const float* g2 = (const float*)d_in[13]; const float* be2 = (const float*)d_in[14];
  const float* g3 = (const float*)d_in[15]; const float* be3 = (const float*)d_in[16];
  const float* g4 = (const float*)d_in[17]; const float* be4 = (const float*)d_in[18];
  const float* sW1 = (const float*)d_in[19]; const float* sb1 = (const float*)d_in[20];
  const float* sW2 = (const float*)d_in[21]; const float* sb2 = (const float*)d_in[22];
  const float* hW1 = (const float*)d_in[23]; const float* hb1 = (const float*)d_in[24];
  const float* hW2 = (const float*)d_in[25]; const float* hb2 = (const float*)d_in[26];

  const int N = in_sizes[0] / 8;
  const int E = in_sizes[1] / 2;
  const int Npad = (N + 127) & ~127;
  const int* srcp = ei;
  const int* dstp = ei + E;

  char* base = (char*)d_ws;
  size_t off = 0;
  auto alloc = [&](size_t bytes) -> void* {
    void* p = base + off;
    off += (bytes + 255) & ~(size_t)255;
    return p;
  };
  unsigned short* Ybf = (unsigned short*)alloc((size_t)Npad * 256 * 2);
  unsigned short* Ahi = (unsigned short*)alloc((size_t)Npad * 256 * 2);
  float* dis  = (float*)alloc((size_t)N * 4);
  int* cnt    = (int*)alloc((size_t)N * 4);
  int* rs     = (int*)alloc((size_t)(N + 1) * 4);
  int* cursor = (int*)alloc((size_t)N * 4);
  int* es     = (int*)alloc((size_t)E * 4);
  int* bsum   = (int*)alloc(1024 * 4);
  int* bsumx  = (int*)alloc(1032 * 4);
  float* xa8  = (float*)alloc((size_t)N * 8 * 4);
  float* statsAll = (float*)alloc(2048 * 4);
  float* ssAll    = (float*)alloc(2048 * 4);
  unsigned short* Wthi = (unsigned short*)alloc(3 * 256 * 256 * 2);
  unsigned short* Wtlo = (unsigned short*)alloc(3 * 256 * 256 * 2);
  int* cntg    = (int*)alloc(2048 * 4);
  int* gstart  = (int*)alloc(2049 * 4);
  float* pooled = (float*)alloc((size_t)2048 * 512 * 4);
  float* s1b    = (float*)alloc((size_t)2048 * 256 * 4);
  float* s2b    = (float*)alloc((size_t)2048 * 128 * 4);
  (void)ws_size; (void)n_in; (void)out_size;

  int nb = (N + TPB - 1) / TPB;
  int eb = (E + TPB - 1) / TPB;
  int nblocks1 = (N + 1023) / 1024;

  k_init<<<nb, TPB, 0, stream>>>(dis, cnt, cntg, statsAll, N);
  k_deg_hist<<<eb, TPB, 0, stream>>>(dstp, dis, cnt, E);
  k_hist_batch<<<nb, TPB, 0, stream>>>(batch, cntg, N);
  k_rsqrt<<<nb, TPB, 0, stream>>>(dis, N);
  k_scan1<<<nblocks1, 256, 0, stream>>>(cnt, rs, bsum, N);
  k_scan_small<<<1, 256, 0, stream>>>(bsum, bsumx, nblocks1);
  k_scan3<<<nb, TPB, 0, stream>>>(rs, bsumx, cursor, N, E);
  k_scatter<<<eb, TPB, 0, stream>>>(srcp, dstp, cursor, es, E);
  k_scan_small<<<1, 256, 0, stream>>>(cntg, gstart, NGRAPH);

  // weight prep (layers 2..4)
  k_wprep<<<256, 256, 0, stream>>>(W2, Wthi + 0 * 65536, Wtlo + 0 * 65536);
  k_wprep<<<256, 256, 0, stream>>>(W3, Wthi + 1 * 65536, Wtlo + 1 * 65536);
  k_wprep<<<256, 256, 0, stream>>>(W4, Wthi + 2 * 65536, Wtlo + 2 * 65536);

  // ---- layer 1: aggregate on D=8, project (fp32), fused stats ----
  k_agg8<<<(N * 8 + TPB - 1) / TPB, TPB, 0, stream>>>(x, dis, rs, es, xa8, N);
  k_gemm8<<<(N + 63) / 64, 256, 0, stream>>>(xa8, W1, b1, Ybf, statsAll, N);
  k_scaleshift<<<1, 256, 0, stream>>>(statsAll, g1, be1, ssAll, N);

  // ---- layers 2..4 ----
  const float* bs_[3] = {b2, b3, b4};
  const float* gs[3]  = {g2, g3, g4};
  const float* bes[3] = {be2, be3, be4};
  dim3 gg((Npad) / 128, 2);
  for (int L = 0; L < 3; ++L) {
    k_agg_bn<<<(N + 3) / 4, 256, 0, stream>>>(Ybf, ssAll + L * 512, dis, rs, es,
                                              Ahi, N);
    k_gemm_mfma<<<gg, 256, 0, stream>>>(Ahi, Wthi + L * 65536, Wtlo + L * 65536,
                                        bs_[L], Ybf, statsAll + (L + 1) * 512, N);
    k_scaleshift<<<1, 256, 0, stream>>>(statsAll + (L + 1) * 512, gs[L], bes[L],
                                        ssAll + (L + 1) * 512, N);
  }

  // ---- pooling (fused BN+ReLU of layer 4) + MLP + heads ----
  k_pool<<<NGRAPH, 256, 0, stream>>>(Ybf, ssAll + 3 * 512, gstart, pooled);
  k_mlp1<<<NGRAPH / 8, 256, 0, stream>>>(pooled, sW1, sb1, s1b);
  k_mlp2<<<NGRAPH / 16, 128, 0, stream>>>(s1b, sW2, sb2, s2b);
  k_heads<<<NGRAPH, 128, 0, stream>>>(s2b, hW1, hb1, hW2, hb2, (float*)d_out);
}

// Round 8
// 652.873 us; speedup vs baseline: 2.1357x; 1.0753x over previous
//
#include <hip/hip_runtime.h>
#include <math.h>

#define TPB 256
#define NGRAPH 2048

typedef __attribute__((ext_vector_type(8))) short bf16x8;
typedef __attribute__((ext_vector_type(4))) float f32x4;

__device__ __forceinline__ unsigned short f2bf(float f) {
  unsigned u = __float_as_uint(f);
  unsigned r = (u + 0x7FFF + ((u >> 16) & 1)) >> 16;
  return (unsigned short)r;
}
__device__ __forceinline__ float bf2f(unsigned short h) {
  return __uint_as_float(((unsigned)h) << 16);
}

#define GLOAD_LDS16(G, L) \
  __builtin_amdgcn_global_load_lds((const __attribute__((address_space(1))) unsigned int*)(G), \
                                   (__attribute__((address_space(3))) unsigned int*)(L), 16, 0, 0)

// ---------------- init / degree / histograms ----------------
__global__ void k_init(float* __restrict__ deg, int* __restrict__ cnt,
                       int* __restrict__ cntg, float* __restrict__ statsAll, int N) {
  int i = blockIdx.x * TPB + threadIdx.x;
  if (i < N) { deg[i] = 1.0f; cnt[i] = 0; }
  if (i < NGRAPH) cntg[i] = 0;
  if (i < 2048) statsAll[i] = 0.f;
}

__global__ void k_deg_hist(const int* __restrict__ dst, float* __restrict__ deg,
                           int* __restrict__ cnt, int E) {
  int e = blockIdx.x * TPB + threadIdx.x;
  if (e < E) {
    int d = dst[e];
    atomicAdd(&deg[d], 1.0f);
    atomicAdd(&cnt[d], 1);
  }
}

__global__ void k_hist_batch(const int* __restrict__ batch, int* __restrict__ cntg, int N) {
  int i = blockIdx.x * TPB + threadIdx.x;
  if (i < N) atomicAdd(&cntg[batch[i]], 1);
}

__global__ void k_rsqrt(float* __restrict__ d, int N) {
  int i = blockIdx.x * TPB + threadIdx.x;
  if (i < N) d[i] = rsqrtf(d[i]);
}

// ---------------- scans ----------------
__global__ void k_scan1(const int* __restrict__ in, int* __restrict__ out,
                        int* __restrict__ bsum, int n) {
  __shared__ int ts[256];
  int tid = threadIdx.x;
  int base = blockIdx.x * 1024 + tid * 4;
  int v0 = (base + 0 < n) ? in[base + 0] : 0;
  int v1 = (base + 1 < n) ? in[base + 1] : 0;
  int v2 = (base + 2 < n) ? in[base + 2] : 0;
  int v3 = (base + 3 < n) ? in[base + 3] : 0;
  int s = v0 + v1 + v2 + v3;
  int run = s;
  ts[tid] = run; __syncthreads();
  for (int off = 1; off < 256; off <<= 1) {
    int add = (tid >= off) ? ts[tid - off] : 0;
    __syncthreads();
    run += add; ts[tid] = run; __syncthreads();
  }
  int acc = run - s;
  if (base + 0 < n) out[base + 0] = acc; acc += v0;
  if (base + 1 < n) out[base + 1] = acc; acc += v1;
  if (base + 2 < n) out[base + 2] = acc; acc += v2;
  if (base + 3 < n) out[base + 3] = acc;
  if (tid == 255) bsum[blockIdx.x] = run;
}

__global__ void k_scan_small(const int* __restrict__ in, int* __restrict__ dst, int n) {
  __shared__ int ts[256];
  int tid = threadIdx.x;
  int chunk = (n + 255) >> 8;
  int start = tid * chunk;
  int s = 0;
  for (int j = 0; j < chunk; ++j) { int idx = start + j; if (idx < n) s += in[idx]; }
  int run = s;
  ts[tid] = run; __syncthreads();
  for (int off = 1; off < 256; off <<= 1) {
    int add = (tid >= off) ? ts[tid - off] : 0;
    __syncthreads();
    run += add; ts[tid] = run; __syncthreads();
  }
  int acc = run - s;
  for (int j = 0; j < chunk; ++j) {
    int idx = start + j;
    if (idx < n) { dst[idx] = acc; acc += in[idx]; }
  }
  if (tid == 255) dst[n] = run;
}

__global__ void k_scan3(int* __restrict__ rs, const int* __restrict__ bsumx,
                        int* __restrict__ cursor, int n, int total) {
  int i = blockIdx.x * TPB + threadIdx.x;
  if (i < n) {
    int v = rs[i] + bsumx[i >> 10];
    rs[i] = v; cursor[i] = v;
  }
  if (i == 0) rs[n] = total;
}

__global__ void k_scatter(const int* __restrict__ src, const int* __restrict__ dst,
                          int* __restrict__ cursor, int* __restrict__ es, int E) {
  int e = blockIdx.x * TPB + threadIdx.x;
  if (e < E) {
    int d = dst[e];
    int p = atomicAdd(&cursor[d], 1);
    es[p] = src[e];
  }
}

// ---------------- weight prep: transpose + hi/lo split ----------------
__global__ __launch_bounds__(256) void k_wprep(const float* __restrict__ W,
    unsigned short* __restrict__ Wthi, unsigned short* __restrict__ Wtlo) {
  int c = blockIdx.x, k = threadIdx.x;
  float w = W[k * 256 + c];
  unsigned short h = f2bf(w);
  Wthi[c * 256 + k] = h;
  Wtlo[c * 256 + k] = f2bf(w - bf2f(h));
}

// ---------------- layer-1 aggregation on D=8 (fp32) ----------------
__global__ void k_agg8(const float* __restrict__ x, const float* __restrict__ dis,
                       const int* __restrict__ rs, const int* __restrict__ es,
                       float* __restrict__ xa8, int N) {
  int t = blockIdx.x * TPB + threadIdx.x;
  int n = t >> 3, c = t & 7;
  if (n >= N) return;
  int e0 = rs[n], e1 = rs[n + 1];
  float acc = 0.f;
  for (int e = e0; e < e1; ++e) {
    int s = es[e];
    acc += dis[s] * x[s * 8 + c];
  }
  float dn = dis[n];
  xa8[n * 8 + c] = dn * acc + dn * dn * x[n * 8 + c];
}

// y[N,256] = xa8[N,8] @ W[8,256] + b, fused BN stats, bf16 output
__global__ __launch_bounds__(256) void k_gemm8(const float* __restrict__ A,
    const float* __restrict__ W, const float* __restrict__ b,
    unsigned short* __restrict__ Ybf, float* __restrict__ stats, int N) {
  __shared__ float Ws[8 * 256];
  __shared__ float bs[256];
  __shared__ float rows[64 * 8];
  int tid = threadIdx.x;
  int row0 = blockIdx.x * 64;
  for (int j = 0; j < 8; ++j) Ws[tid + j * 256] = W[tid + j * 256];
  bs[tid] = b[tid];
  int lim = N * 8;
  int o0 = row0 * 8 + tid, o1 = o0 + 256;
  rows[tid] = (o0 < lim) ? A[o0] : 0.f;
  rows[tid + 256] = (o1 < lim) ? A[o1] : 0.f;
  __syncthreads();
  float s = 0.f, s2 = 0.f;
  for (int r = 0; r < 64; ++r) {
    int row = row0 + r;
    if (row >= N) break;
    float acc = bs[tid];
#pragma unroll
    for (int k = 0; k < 8; ++k) acc += rows[r * 8 + k] * Ws[k * 256 + tid];
    Ybf[(size_t)row * 256 + tid] = f2bf(acc);
    s += acc; s2 += acc * acc;
  }
  atomicAdd(&stats[tid], s);
  atomicAdd(&stats[256 + tid], s2);
}

// ---------------- fused BN+ReLU aggregation, wave per node ----------------
__global__ __launch_bounds__(256) void k_agg_bn(const unsigned short* __restrict__ Ybf,
    const float* __restrict__ ss, const float* __restrict__ dis,
    const int* __restrict__ rs, const int* __restrict__ es,
    unsigned short* __restrict__ Ahi, int N) {
  int lane = threadIdx.x & 63;
  int n = __builtin_amdgcn_readfirstlane(blockIdx.x * 4 + (threadIdx.x >> 6));
  if (n >= N) return;
  int c = lane * 4;
  float4 sc = *(const float4*)&ss[c];
  float4 sh = *(const float4*)&ss[256 + c];
  int e0 = rs[n], e1 = rs[n + 1];
  float4 a = make_float4(0.f, 0.f, 0.f, 0.f);
  for (int e = e0; e < e1; ++e) {
    int s = es[e];
    float d = dis[s];
    ushort4 yb = *(const ushort4*)&Ybf[(size_t)s * 256 + c];
    a.x += d * fmaxf(fmaf(bf2f(yb.x), sc.x, sh.x), 0.f);
    a.y += d * fmaxf(fmaf(bf2f(yb.y), sc.y, sh.y), 0.f);
    a.z += d * fmaxf(fmaf(bf2f(yb.z), sc.z, sh.z), 0.f);
    a.w += d * fmaxf(fmaf(bf2f(yb.w), sc.w, sh.w), 0.f);
  }
  float dn = dis[n];
  float dn2 = dn * dn;
  ushort4 yb = *(const ushort4*)&Ybf[(size_t)n * 256 + c];
  float4 r;
  r.x = dn * a.x + dn2 * fmaxf(fmaf(bf2f(yb.x), sc.x, sh.x), 0.f);
  r.y = dn * a.y + dn2 * fmaxf(fmaf(bf2f(yb.y), sc.y, sh.y), 0.f);
  r.z = dn * a.z + dn2 * fmaxf(fmaf(bf2f(yb.z), sc.z, sh.z), 0.f);
  r.w = dn * a.w + dn2 * fmaxf(fmaf(bf2f(yb.w), sc.w, sh.w), 0.f);
  ushort4 h;
  h.x = f2bf(r.x); h.y = f2bf(r.y); h.z = f2bf(r.z); h.w = f2bf(r.w);
  *(ushort4*)&Ahi[(size_t)n * 256 + c] = h;
}

// ---------------- MFMA GEMM: Y[M,256] = A[M,256] @ (Wh+Wl)[256,256] + b
// 256x256 full-width tile, 8 waves (2 row-halves x 4 col-quarters), per-wave
// 128x64 output (128 MFMA per K-step). Counted-vmcnt pipeline: B-fragment
// loads are issued BEFORE the vmcnt(4), so one wait covers {B, prev tile};
// the fresh prefetch (newest 4) stays in flight across the barrier.
__global__ __launch_bounds__(512) void k_gemm_mfma(
    const unsigned short* __restrict__ A,
    const unsigned short* __restrict__ Wthi, const unsigned short* __restrict__ Wtlo,
    const float* __restrict__ bias, unsigned short* __restrict__ Ybf,
    float* __restrict__ stats, int M) {
  __shared__ unsigned short As[2][256 * 64];  // dbuf 2x32KB, xor-swizzled rows
  const int tid = threadIdx.x;
  const int lane = tid & 63;
  const int wid = tid >> 6;        // 0..7
  const int wr = wid >> 2;         // 0..1  (128-row half)
  const int wc = wid & 3;          // 0..3  (64-col quarter)
  const int l15 = lane & 15, lg = lane >> 4;
  const int row0 = blockIdx.x * 256;

  f32x4 acc[8][4] = {};

  // stage one 256x64 bf16 K-tile: 4 x gload_lds16 per thread (512 thr)
  // linear LDS dest + inverse-swizzled global source (rule #21)
#define STAGE(buf, k0)                                                        \
  {                                                                           \
    _Pragma("unroll")                                                         \
    for (int it = 0; it < 4; ++it) {                                          \
      int L = it * 8192 + tid * 16;                                           \
      int row = L >> 7;                                                       \
      int kb = L & 127;                                                       \
      int skb = kb ^ ((row & 7) << 4);                                        \
      GLOAD_LDS16(A + (size_t)(row0 + row) * 256 + (k0) + (skb >> 1),         \
                  &As[buf][L >> 1]);                                          \
    }                                                                         \
  }

  STAGE(0, 0);
  int cur = 0;
#pragma unroll
  for (int t = 0; t < 4; ++t) {
    const int k0 = t * 64;
    // B-fragment loads FIRST (L2-hot W planes) so vmcnt(4) covers them too
    bf16x8 bh[2][4], bl[2][4];
#pragma unroll
    for (int kk = 0; kk < 2; ++kk)
#pragma unroll
      for (int n = 0; n < 4; ++n) {
        int col = wc * 64 + n * 16 + l15;
        int kidx = k0 + kk * 32 + lg * 8;
        bh[kk][n] = *(const bf16x8*)(Wthi + (size_t)col * 256 + kidx);
        bl[kk][n] = *(const bf16x8*)(Wtlo + (size_t)col * 256 + kidx);
      }
    if (t < 3) {
      STAGE(cur ^ 1, k0 + 64);  // prefetch next tile; newest 4 stay in flight
      asm volatile("s_waitcnt vmcnt(4)" ::: "memory");
    } else {
      asm volatile("s_waitcnt vmcnt(0)" ::: "memory");
    }
    __builtin_amdgcn_s_barrier();  // all waves' tile-t loads landed
#pragma unroll
    for (int kk = 0; kk < 2; ++kk) {
#pragma unroll
      for (int m = 0; m < 8; ++m) {
        int rl = wr * 128 + m * 16 + l15;
        int kb = (kk * 64 + lg * 16) ^ ((rl & 7) << 4);  // swizzled read
        bf16x8 ah = *(const bf16x8*)&As[cur][rl * 64 + (kb >> 1)];
#pragma unroll
        for (int n = 0; n < 4; ++n) {
          acc[m][n] = __builtin_amdgcn_mfma_f32_16x16x32_bf16(ah, bh[kk][n], acc[m][n], 0, 0, 0);
          acc[m][n] = __builtin_amdgcn_mfma_f32_16x16x32_bf16(ah, bl[kk][n], acc[m][n], 0, 0, 0);
        }
      }
    }
    // this wave's ds_reads of buf(cur) done before signaling arrival
    asm volatile("s_waitcnt lgkmcnt(0)" ::: "memory");
    __builtin_amdgcn_s_barrier();
    cur ^= 1;
  }

  // epilogue: bias, bf16 store, BN partial stats (exact fp32)
  float* sred = (float*)&As[0][0];  // 512 floats
  sred[tid] = 0.f;
  __syncthreads();
#pragma unroll
  for (int n = 0; n < 4; ++n) {
    int col = wc * 64 + n * 16 + l15;
    float bv = bias[col];
    float s = 0.f, s2 = 0.f;
#pragma unroll
    for (int m = 0; m < 8; ++m) {
      int rbase = row0 + wr * 128 + m * 16 + lg * 4;
      f32x4 v = acc[m][n];
#pragma unroll
      for (int j = 0; j < 4; ++j) {
        int r = rbase + j;
        if (r < M) {
          float val = v[j] + bv;
          Ybf[(size_t)r * 256 + col] = f2bf(val);
          s += val; s2 += val * val;
        }
      }
    }
    atomicAdd(&sred[col], s);
    atomicAdd(&sred[256 + col], s2);
  }
  __syncthreads();
  atomicAdd(&stats[tid], sred[tid]);  // tid<512 covers both halves
}

// ---------------- BN scale/shift ----------------
__global__ void k_scaleshift(const float* __restrict__ stats, const float* __restrict__ g,
                             const float* __restrict__ be, float* __restrict__ ss, int N) {
  int c = threadIdx.x;
  float inv = 1.0f / (float)N;
  float mean = stats[c] * inv;
  float var = stats[256 + c] * inv - mean * mean;
  var = fmaxf(var, 0.f);
  float sc = g[c] * rsqrtf(var + 1e-5f);
  ss[c] = sc;
  ss[256 + c] = be[c] - mean * sc;
}

// ---------------- pooling with fused BN+ReLU (bf16 input) ----------------
__global__ __launch_bounds__(256) void k_pool(const unsigned short* __restrict__ Ybf,
    const float* __restrict__ ss, const int* __restrict__ gstart,
    float* __restrict__ pooled) {
  int g = blockIdx.x, c = threadIdx.x;
  float sc = ss[c], sh = ss[256 + c];
  int n0 = gstart[g], n1 = gstart[g + 1];
  float s = 0.f, m = 0.f;
  for (int n = n0; n < n1; ++n) {
    float v = fmaxf(fmaf(bf2f(Ybf[(size_t)n * 256 + c]), sc, sh), 0.f);
    s += v; m = fmaxf(m, v);
  }
  float cnt = (float)(n1 - n0);
  pooled[g * 512 + c] = s / fmaxf(cnt, 1.0f);
  pooled[g * 512 + 256 + c] = m;
}

// ---------------- MLP + heads ----------------
__global__ __launch_bounds__(256) void k_mlp1(const float* __restrict__ P,
    const float* __restrict__ W, const float* __restrict__ b, float* __restrict__ O) {
  __shared__ float Ps[8 * 512];
  int tid = threadIdx.x;
  int g0 = blockIdx.x * 8;
  for (int j = 0; j < 16; ++j) Ps[tid + j * 256] = P[g0 * 512 + tid + j * 256];
  __syncthreads();
  float acc[8];
  float bb = b[tid];
#pragma unroll
  for (int gi = 0; gi < 8; ++gi) acc[gi] = bb;
  for (int k = 0; k < 512; ++k) {
    float w = W[k * 256 + tid];
#pragma unroll
    for (int gi = 0; gi < 8; ++gi) acc[gi] += Ps[gi * 512 + k] * w;
  }
  for (int gi = 0; gi < 8; ++gi)
    O[(g0 + gi) * 256 + tid] = fmaxf(acc[gi], 0.f);
}

__global__ __launch_bounds__(128) void k_mlp2(const float* __restrict__ S,
    const float* __restrict__ W, const float* __restrict__ b, float* __restrict__ O) {
  __shared__ float Ss[16 * 256];
  int tid = threadIdx.x;
  int g0 = blockIdx.x * 16;
  for (int j = 0; j < 32; ++j) Ss[tid + j * 128] = S[g0 * 256 + tid + j * 128];
  __syncthreads();
  float acc[16];
  float bb = b[tid];
#pragma unroll
  for (int gi = 0; gi < 16; ++gi) acc[gi] = bb;
  for (int k = 0; k < 256; ++k) {
    float w = W[k * 128 + tid];
#pragma unroll
    for (int gi = 0; gi < 16; ++gi) acc[gi] += Ss[gi * 256 + k] * w;
  }
  for (int gi = 0; gi < 16; ++gi)
    O[(g0 + gi) * 128 + tid] = fmaxf(acc[gi], 0.f);
}

__global__ __launch_bounds__(128) void k_heads(const float* __restrict__ S,
    const float* __restrict__ hW1, const float* __restrict__ hb1,
    const float* __restrict__ hW2, const float* __restrict__ hb2,
    float* __restrict__ out) {
  __shared__ float ssm[128];
  __shared__ float t1[96];
  int g = blockIdx.x, tid = threadIdx.x;
  ssm[tid] = S[g * 128 + tid];
  __syncthreads();
  if (tid < 96) {
    int t = tid >> 5, o = tid & 31;
    float acc = hb1[t * 32 + o];
    for (int k = 0; k < 128; ++k) acc += ssm[k] * hW1[t * 4096 + k * 32 + o];
    t1[tid] = fmaxf(acc, 0.f);
  }
  __syncthreads();
  if (tid < 3) {
    float acc = hb2[tid];
    for (int o = 0; o < 32; ++o) acc += t1[tid * 32 + o] * hW2[tid * 32 + o];
    out[tid * NGRAPH + g] = acc;
  }
}

// ---------------- host launcher ----------------
extern "C" void kernel_launch(void* const* d_in, const int* in_sizes, int n_in,
                              void* d_out, int out_size, void* d_ws, size_t ws_size,
                              hipStream_t stream) {
  const float* x   = (const float*)d_in[0];
  const int* ei    = (const int*)d_in[1];
  const int* batch = (const int*)d_in[2];
  const float* W1 = (const float*)d_in[3];  const float* b1 = (const float*)d_in[4];
  const float* W2 = (const float*)d_in[5];  const float* b2 = (const float*)d_in[6];
  const float* W3 = (const float*)d_in[7];  const float* b3 = (const float*)d_in[8];
  const float* W4 = (const float*)d_in[9];  const float* b4 = (const float*)d_in[10];
  const float* g1 = (const float*)d_in[11]; const float* be1 = (const float*)d_in[12];
  const float* g2 = (const float*)d_in[13]; const float* be2 = (const float*)d_in[14];
  const float* g3 = (const float*)d_in[15]; const float* be3 = (const float*)d_in[16];
  const float* g4 = (const float*)d_in[17]; const float* be4 = (const float*)d_in[18];
  const float* sW1 = (const float*)d_in[19]; const float* sb1 = (const float*)d_in[20];
  const float* sW2 = (const float*)d_in[21]; const float* sb2 = (const float*)d_in[22];
  const float* hW1 = (const float*)d_in[23]; const float* hb1 = (const float*)d_in[24];
  const float* hW2 = (const float*)d_in[25]; const float* hb2 = (const float*)d_in[26];

  const int N = in_sizes[0] / 8;
  const int E = in_sizes[1] / 2;
  const int Npad = (N + 255) & ~255;
  const int* srcp = ei;
  const int* dstp = ei + E;

  char* base = (char*)d_ws;
  size_t off = 0;
  auto alloc = [&](size_t bytes) -> void* {
    void* p = base + off;
    off += (bytes + 255) & ~(size_t)255;
    return p;
  };
  unsigned short* Ybf = (unsigned short*)alloc((size_t)Npad * 256 * 2);
  unsigned short* Ahi = (unsigned short*)alloc((size_t)Npad * 256 * 2);
  float* dis  = (float*)alloc((size_t)N * 4);
  int* cnt    = (int*)alloc((size_t)N * 4);
  int* rs     = (int*)alloc((size_t)(N + 1) * 4);
  int* cursor = (int*)alloc((size_t)N * 4);
  int* es     = (int*)alloc((size_t)E * 4);
  int* bsum   = (int*)alloc(1024 * 4);
  int* bsumx  = (int*)alloc(1032 * 4);
  float* xa8  = (float*)alloc((size_t)N * 8 * 4);
  float* statsAll = (float*)alloc(2048 * 4);
  float* ssAll    = (float*)alloc(2048 * 4);
  unsigned short* Wthi = (unsigned short*)alloc(3 * 256 * 256 * 2);
  unsigned short* Wtlo = (unsigned short*)alloc(3 * 256 * 256 * 2);
  int* cntg    = (int*)alloc(2048 * 4);
  int* gstart  = (int*)alloc(2049 * 4);
  float* pooled = (float*)alloc((size_t)2048 * 512 * 4);
  float* s1b    = (float*)alloc((size_t)2048 * 256 * 4);
  float* s2b    = (float*)alloc((size_t)2048 * 128 * 4);
  (void)ws_size; (void)n_in; (void)out_size;

  int nb = (N + TPB - 1) / TPB;
  int eb = (E + TPB - 1) / TPB;
  int nblocks1 = (N + 1023) / 1024;

  k_init<<<nb, TPB, 0, stream>>>(dis, cnt, cntg, statsAll, N);
  k_deg_hist<<<eb, TPB, 0, stream>>>(dstp, dis, cnt, E);
  k_hist_batch<<<nb, TPB, 0, stream>>>(batch, cntg, N);
  k_rsqrt<<<nb, TPB, 0, stream>>>(dis, N);
  k_scan1<<<nblocks1, 256, 0, stream>>>(cnt, rs, bsum, N);
  k_scan_small<<<1, 256, 0, stream>>>(bsum, bsumx, nblocks1);
  k_scan3<<<nb, TPB, 0, stream>>>(rs, bsumx, cursor, N, E);
  k_scatter<<<eb, TPB, 0, stream>>>(srcp, dstp, cursor, es, E);
  k_scan_small<<<1, 256, 0, stream>>>(cntg, gstart, NGRAPH);

  // weight prep (layers 2..4)
  k_wprep<<<256, 256, 0, stream>>>(W2, Wthi + 0 * 65536, Wtlo + 0 * 65536);
  k_wprep<<<256, 256, 0, stream>>>(W3, Wthi + 1 * 65536, Wtlo + 1 * 65536);
  k_wprep<<<256, 256, 0, stream>>>(W4, Wthi + 2 * 65536, Wtlo + 2 * 65536);

  // ---- layer 1: aggregate on D=8, project (fp32), fused stats ----
  k_agg8<<<(N * 8 + TPB - 1) / TPB, TPB, 0, stream>>>(x, dis, rs, es, xa8, N);
  k_gemm8<<<(N + 63) / 64, 256, 0, stream>>>(xa8, W1, b1, Ybf, statsAll, N);
  k_scaleshift<<<1, 256, 0, stream>>>(statsAll, g1, be1, ssAll, N);

  // ---- layers 2..4 ----
  const float* bs_[3] = {b2, b3, b4};
  const float* gs[3]  = {g2, g3, g4};
  const float* bes[3] = {be2, be3, be4};
  for (int L = 0; L < 3; ++L) {
    k_agg_bn<<<(N + 3) / 4, 256, 0, stream>>>(Ybf, ssAll + L * 512, dis, rs, es,
                                              Ahi, N);
    k_gemm_mfma<<<Npad / 256, 512, 0, stream>>>(Ahi, Wthi + L * 65536, Wtlo + L * 65536,
                                                bs_[L], Ybf, statsAll + (L + 1) * 512, N);
    k_scaleshift<<<1, 256, 0, stream>>>(statsAll + (L + 1) * 512, gs[L], bes[L],
                                        ssAll + (L + 1) * 512, N);
  }

  // ---- pooling (fused BN+ReLU of layer 4) + MLP + heads ----
  k_pool<<<NGRAPH, 256, 0, stream>>>(Ybf, ssAll + 3 * 512, gstart, pooled);
  k_mlp1<<<NGRAPH / 8, 256, 0, stream>>>(pooled, sW1, sb1, s1b);
  k_mlp2<<<NGRAPH / 16, 128, 0, stream>>>(s1b, sW2, sb2, s2b);
  k_heads<<<NGRAPH, 128, 0, stream>>>(s2b, hW1, hb1, hW2, hb2, (float*)d_out);
}

// Round 9
// 622.310 us; speedup vs baseline: 2.2406x; 1.0491x over previous
//
#include <hip/hip_runtime.h>
#include <math.h>

#define TPB 256
#define NGRAPH 2048

typedef __attribute__((ext_vector_type(8))) short bf16x8;
typedef __attribute__((ext_vector_type(4))) float f32x4;

__device__ __forceinline__ unsigned short f2bf(float f) {
  unsigned u = __float_as_uint(f);
  unsigned r = (u + 0x7FFF + ((u >> 16) & 1)) >> 16;
  return (unsigned short)r;
}
__device__ __forceinline__ float bf2f(unsigned short h) {
  return __uint_as_float(((unsigned)h) << 16);
}

#define GLOAD_LDS16(G, L) \
  __builtin_amdgcn_global_load_lds((const __attribute__((address_space(1))) unsigned int*)(G), \
                                   (__attribute__((address_space(3))) unsigned int*)(L), 16, 0, 0)

// ---------------- init / degree / histograms ----------------
__global__ void k_init(float* __restrict__ deg, int* __restrict__ cnt,
                       int* __restrict__ cntg, float* __restrict__ statsAll, int N) {
  int i = blockIdx.x * TPB + threadIdx.x;
  if (i < N) { deg[i] = 1.0f; cnt[i] = 0; }
  if (i < NGRAPH) cntg[i] = 0;
  if (i < 2048) statsAll[i] = 0.f;
}

__global__ void k_deg_hist(const int* __restrict__ dst, float* __restrict__ deg,
                           int* __restrict__ cnt, int E) {
  int e = blockIdx.x * TPB + threadIdx.x;
  if (e < E) {
    int d = dst[e];
    atomicAdd(&deg[d], 1.0f);
    atomicAdd(&cnt[d], 1);
  }
}

__global__ void k_hist_batch(const int* __restrict__ batch, int* __restrict__ cntg, int N) {
  int i = blockIdx.x * TPB + threadIdx.x;
  if (i < N) atomicAdd(&cntg[batch[i]], 1);
}

__global__ void k_rsqrt(float* __restrict__ d, int N) {
  int i = blockIdx.x * TPB + threadIdx.x;
  if (i < N) d[i] = rsqrtf(d[i]);
}

// ---------------- scans ----------------
__global__ void k_scan1(const int* __restrict__ in, int* __restrict__ out,
                        int* __restrict__ bsum, int n) {
  __shared__ int ts[256];
  int tid = threadIdx.x;
  int base = blockIdx.x * 1024 + tid * 4;
  int v0 = (base + 0 < n) ? in[base + 0] : 0;
  int v1 = (base + 1 < n) ? in[base + 1] : 0;
  int v2 = (base + 2 < n) ? in[base + 2] : 0;
  int v3 = (base + 3 < n) ? in[base + 3] : 0;
  int s = v0 + v1 + v2 + v3;
  int run = s;
  ts[tid] = run; __syncthreads();
  for (int off = 1; off < 256; off <<= 1) {
    int add = (tid >= off) ? ts[tid - off] : 0;
    __syncthreads();
    run += add; ts[tid] = run; __syncthreads();
  }
  int acc = run - s;
  if (base + 0 < n) out[base + 0] = acc; acc += v0;
  if (base + 1 < n) out[base + 1] = acc; acc += v1;
  if (base + 2 < n) out[base + 2] = acc; acc += v2;
  if (base + 3 < n) out[base + 3] = acc;
  if (tid == 255) bsum[blockIdx.x] = run;
}

__global__ void k_scan_small(const int* __restrict__ in, int* __restrict__ dst, int n) {
  __shared__ int ts[256];
  int tid = threadIdx.x;
  int chunk = (n + 255) >> 8;
  int start = tid * chunk;
  int s = 0;
  for (int j = 0; j < chunk; ++j) { int idx = start + j; if (idx < n) s += in[idx]; }
  int run = s;
  ts[tid] = run; __syncthreads();
  for (int off = 1; off < 256; off <<= 1) {
    int add = (tid >= off) ? ts[tid - off] : 0;
    __syncthreads();
    run += add; ts[tid] = run; __syncthreads();
  }
  int acc = run - s;
  for (int j = 0; j < chunk; ++j) {
    int idx = start + j;
    if (idx < n) { dst[idx] = acc; acc += in[idx]; }
  }
  if (tid == 255) dst[n] = run;
}

__global__ void k_scan3(int* __restrict__ rs, const int* __restrict__ bsumx,
                        int* __restrict__ cursor, int n, int total) {
  int i = blockIdx.x * TPB + threadIdx.x;
  if (i < n) {
    int v = rs[i] + bsumx[i >> 10];
    rs[i] = v; cursor[i] = v;
  }
  if (i == 0) rs[n] = total;
}

__global__ void k_scatter(const int* __restrict__ src, const int* __restrict__ dst,
                          int* __restrict__ cursor, int* __restrict__ es, int E) {
  int e = blockIdx.x * TPB + threadIdx.x;
  if (e < E) {
    int d = dst[e];
    int p = atomicAdd(&cursor[d], 1);
    es[p] = src[e];
  }
}

// ---------------- weight prep: transpose + hi/lo split ----------------
__global__ __launch_bounds__(256) void k_wprep(const float* __restrict__ W,
    unsigned short* __restrict__ Wthi, unsigned short* __restrict__ Wtlo) {
  int c = blockIdx.x, k = threadIdx.x;
  float w = W[k * 256 + c];
  unsigned short h = f2bf(w);
  Wthi[c * 256 + k] = h;
  Wtlo[c * 256 + k] = f2bf(w - bf2f(h));
}

// ---------------- layer-1 aggregation on D=8 (fp32) ----------------
__global__ void k_agg8(const float* __restrict__ x, const float* __restrict__ dis,
                       const int* __restrict__ rs, const int* __restrict__ es,
                       float* __restrict__ xa8, int N) {
  int t = blockIdx.x * TPB + threadIdx.x;
  int n = t >> 3, c = t & 7;
  if (n >= N) return;
  int e0 = rs[n], e1 = rs[n + 1];
  float acc = 0.f;
  for (int e = e0; e < e1; ++e) {
    int s = es[e];
    acc += dis[s] * x[s * 8 + c];
  }
  float dn = dis[n];
  xa8[n * 8 + c] = dn * acc + dn * dn * x[n * 8 + c];
}

// y[N,256] = xa8[N,8] @ W[8,256] + b, fused BN stats, bf16 output
__global__ __launch_bounds__(256) void k_gemm8(const float* __restrict__ A,
    const float* __restrict__ W, const float* __restrict__ b,
    unsigned short* __restrict__ Ybf, float* __restrict__ stats, int N) {
  __shared__ float Ws[8 * 256];
  __shared__ float bs[256];
  __shared__ float rows[64 * 8];
  int tid = threadIdx.x;
  int row0 = blockIdx.x * 64;
  for (int j = 0; j < 8; ++j) Ws[tid + j * 256] = W[tid + j * 256];
  bs[tid] = b[tid];
  int lim = N * 8;
  int o0 = row0 * 8 + tid, o1 = o0 + 256;
  rows[tid] = (o0 < lim) ? A[o0] : 0.f;
  rows[tid + 256] = (o1 < lim) ? A[o1] : 0.f;
  __syncthreads();
  float s = 0.f, s2 = 0.f;
  for (int r = 0; r < 64; ++r) {
    int row = row0 + r;
    if (row >= N) break;
    float acc = bs[tid];
#pragma unroll
    for (int k = 0; k < 8; ++k) acc += rows[r * 8 + k] * Ws[k * 256 + tid];
    Ybf[(size_t)row * 256 + tid] = f2bf(acc);
    s += acc; s2 += acc * acc;
  }
  atomicAdd(&stats[tid], s);
  atomicAdd(&stats[256 + tid], s2);
}

// ---------------- fused BN+ReLU aggregation, wave per node ----------------
__global__ __launch_bounds__(256) void k_agg_bn(const unsigned short* __restrict__ Ybf,
    const float* __restrict__ ss, const float* __restrict__ dis,
    const int* __restrict__ rs, const int* __restrict__ es,
    unsigned short* __restrict__ Ahi, int N) {
  int lane = threadIdx.x & 63;
  int n = __builtin_amdgcn_readfirstlane(blockIdx.x * 4 + (threadIdx.x >> 6));
  if (n >= N) return;
  int c = lane * 4;
  float4 sc = *(const float4*)&ss[c];
  float4 sh = *(const float4*)&ss[256 + c];
  int e0 = rs[n], e1 = rs[n + 1];
  float4 a = make_float4(0.f, 0.f, 0.f, 0.f);
  for (int e = e0; e < e1; ++e) {
    int s = es[e];
    float d = dis[s];
    ushort4 yb = *(const ushort4*)&Ybf[(size_t)s * 256 + c];
    a.x += d * fmaxf(fmaf(bf2f(yb.x), sc.x, sh.x), 0.f);
    a.y += d * fmaxf(fmaf(bf2f(yb.y), sc.y, sh.y), 0.f);
    a.z += d * fmaxf(fmaf(bf2f(yb.z), sc.z, sh.z), 0.f);
    a.w += d * fmaxf(fmaf(bf2f(yb.w), sc.w, sh.w), 0.f);
  }
  float dn = dis[n];
  float dn2 = dn * dn;
  ushort4 yb = *(const ushort4*)&Ybf[(size_t)n * 256 + c];
  float4 r;
  r.x = dn * a.x + dn2 * fmaxf(fmaf(bf2f(yb.x), sc.x, sh.x), 0.f);
  r.y = dn * a.y + dn2 * fmaxf(fmaf(bf2f(yb.y), sc.y, sh.y), 0.f);
  r.z = dn * a.z + dn2 * fmaxf(fmaf(bf2f(yb.z), sc.z, sh.z), 0.f);
  r.w = dn * a.w + dn2 * fmaxf(fmaf(bf2f(yb.w), sc.w, sh.w), 0.f);
  ushort4 h;
  h.x = f2bf(r.x); h.y = f2bf(r.y); h.z = f2bf(r.z); h.w = f2bf(r.w);
  *(ushort4*)&Ahi[(size_t)n * 256 + c] = h;
}

// ---------------- MFMA GEMM: Y[M,256] = A[M,256] @ (Wh+Wl)[256,256] + b
// 256x256 full-width tile, 8 waves. Counted-vmcnt K-loop (unchanged from r8).
// NEW: coalesced epilogue — fragments -> LDS (bf16) -> full-line int4 stores.
__global__ __launch_bounds__(512) void k_gemm_mfma(
    const unsigned short* __restrict__ A,
    const unsigned short* __restrict__ Wthi, const unsigned short* __restrict__ Wtlo,
    const float* __restrict__ bias, unsigned short* __restrict__ Ybf,
    float* __restrict__ stats, int M) {
  __shared__ unsigned short As[2][256 * 64];  // dbuf 2x32KB, xor-swizzled rows
  __shared__ float sred2[512];
  const int tid = threadIdx.x;
  const int lane = tid & 63;
  const int wid = tid >> 6;        // 0..7
  const int wr = wid >> 2;         // 0..1  (128-row half)
  const int wc = wid & 3;          // 0..3  (64-col quarter)
  const int l15 = lane & 15, lg = lane >> 4;
  const int row0 = blockIdx.x * 256;

  f32x4 acc[8][4] = {};

  // stage one 256x64 bf16 K-tile: 4 x gload_lds16 per thread (512 thr)
  // linear LDS dest + inverse-swizzled global source (rule #21)
#define STAGE(buf, k0)                                                        \
  {                                                                           \
    _Pragma("unroll")                                                         \
    for (int it = 0; it < 4; ++it) {                                          \
      int L = it * 8192 + tid * 16;                                           \
      int row = L >> 7;                                                       \
      int kb = L & 127;                                                       \
      int skb = kb ^ ((row & 7) << 4);                                        \
      GLOAD_LDS16(A + (size_t)(row0 + row) * 256 + (k0) + (skb >> 1),         \
                  &As[buf][L >> 1]);                                          \
    }                                                                         \
  }

  STAGE(0, 0);
  int cur = 0;
#pragma unroll
  for (int t = 0; t < 4; ++t) {
    const int k0 = t * 64;
    // B-fragment loads FIRST (L2-hot W planes) so vmcnt(4) covers them too
    bf16x8 bh[2][4], bl[2][4];
#pragma unroll
    for (int kk = 0; kk < 2; ++kk)
#pragma unroll
      for (int n = 0; n < 4; ++n) {
        int col = wc * 64 + n * 16 + l15;
        int kidx = k0 + kk * 32 + lg * 8;
        bh[kk][n] = *(const bf16x8*)(Wthi + (size_t)col * 256 + kidx);
        bl[kk][n] = *(const bf16x8*)(Wtlo + (size_t)col * 256 + kidx);
      }
    if (t < 3) {
      STAGE(cur ^ 1, k0 + 64);  // prefetch next tile; newest 4 stay in flight
      asm volatile("s_waitcnt vmcnt(4)" ::: "memory");
    } else {
      asm volatile("s_waitcnt vmcnt(0)" ::: "memory");
    }
    __builtin_amdgcn_s_barrier();  // all waves' tile-t loads landed
#pragma unroll
    for (int kk = 0; kk < 2; ++kk) {
#pragma unroll
      for (int m = 0; m < 8; ++m) {
        int rl = wr * 128 + m * 16 + l15;
        int kb = (kk * 64 + lg * 16) ^ ((rl & 7) << 4);  // swizzled read
        bf16x8 ah = *(const bf16x8*)&As[cur][rl * 64 + (kb >> 1)];
#pragma unroll
        for (int n = 0; n < 4; ++n) {
          acc[m][n] = __builtin_amdgcn_mfma_f32_16x16x32_bf16(ah, bh[kk][n], acc[m][n], 0, 0, 0);
          acc[m][n] = __builtin_amdgcn_mfma_f32_16x16x32_bf16(ah, bl[kk][n], acc[m][n], 0, 0, 0);
        }
      }
    }
    // this wave's ds_reads of buf(cur) done before signaling arrival
    asm volatile("s_waitcnt lgkmcnt(0)" ::: "memory");
    __builtin_amdgcn_s_barrier();
    cur ^= 1;
  }

  // ---- coalesced epilogue ----
  // stats from exact fp32 acc (guarded row<M); bf16 tile staged in LDS
  // (reuse As = 64KB = 128 rows x 256 cols), stored as full-line int4.
  sred2[tid] = 0.f;
  unsigned short* stage = (unsigned short*)&As[0][0];
#pragma unroll
  for (int h = 0; h < 2; ++h) {
    __syncthreads();  // h=0: K-loop LDS reads + sred2 init done; h=1: prev stores done
    if (wr == h) {
#pragma unroll
      for (int n = 0; n < 4; ++n) {
        int col = wc * 64 + n * 16 + l15;
        float bv = bias[col];
        float s = 0.f, s2 = 0.f;
#pragma unroll
        for (int m = 0; m < 8; ++m) {
          int rloc = m * 16 + lg * 4;  // local row in this 128-row half
          f32x4 v = acc[m][n];
#pragma unroll
          for (int j = 0; j < 4; ++j) {
            float val = v[j] + bv;
            stage[(rloc + j) * 256 + col] = f2bf(val);
            if (row0 + h * 128 + rloc + j < M) { s += val; s2 += val * val; }
          }
        }
        atomicAdd(&sred2[col], s);
        atomicAdd(&sred2[256 + col], s2);
      }
    }
    __syncthreads();  // stage filled
#pragma unroll
    for (int it = 0; it < 8; ++it) {
      int off = it * 8192 + tid * 16;  // byte offset in 64KB stage
      int r = off >> 9;                // /512B per row
      int grow = row0 + h * 128 + r;
      if (grow < M)
        *(int4*)((char*)Ybf + (size_t)grow * 512 + (off & 511)) =
            *(const int4*)((const char*)stage + off);
    }
  }
  __syncthreads();
  atomicAdd(&stats[tid], sred2[tid]);  // tid<512 covers [s|s2]
}

// ---------------- BN scale/shift ----------------
__global__ void k_scaleshift(const float* __restrict__ stats, const float* __restrict__ g,
                             const float* __restrict__ be, float* __restrict__ ss, int N) {
  int c = threadIdx.x;
  float inv = 1.0f / (float)N;
  float mean = stats[c] * inv;
  float var = stats[256 + c] * inv - mean * mean;
  var = fmaxf(var, 0.f);
  float sc = g[c] * rsqrtf(var + 1e-5f);
  ss[c] = sc;
  ss[256 + c] = be[c] - mean * sc;
}

// ---------------- pooling with fused BN+ReLU (bf16 input) ----------------
__global__ __launch_bounds__(256) void k_pool(const unsigned short* __restrict__ Ybf,
    const float* __restrict__ ss, const int* __restrict__ gstart,
    float* __restrict__ pooled) {
  int g = blockIdx.x, c = threadIdx.x;
  float sc = ss[c], sh = ss[256 + c];
  int n0 = gstart[g], n1 = gstart[g + 1];
  float s = 0.f, m = 0.f;
  for (int n = n0; n < n1; ++n) {
    float v = fmaxf(fmaf(bf2f(Ybf[(size_t)n * 256 + c]), sc, sh), 0.f);
    s += v; m = fmaxf(m, v);
  }
  float cnt = (float)(n1 - n0);
  pooled[g * 512 + c] = s / fmaxf(cnt, 1.0f);
  pooled[g * 512 + 256 + c] = m;
}

// ---------------- MLP + heads ----------------
__global__ __launch_bounds__(256) void k_mlp1(const float* __restrict__ P,
    const float* __restrict__ W, const float* __restrict__ b, float* __restrict__ O) {
  __shared__ float Ps[8 * 512];
  int tid = threadIdx.x;
  int g0 = blockIdx.x * 8;
  for (int j = 0; j < 16; ++j) Ps[tid + j * 256] = P[g0 * 512 + tid + j * 256];
  __syncthreads();
  float acc[8];
  float bb = b[tid];
#pragma unroll
  for (int gi = 0; gi < 8; ++gi) acc[gi] = bb;
  for (int k = 0; k < 512; ++k) {
    float w = W[k * 256 + tid];
#pragma unroll
    for (int gi = 0; gi < 8; ++gi) acc[gi] += Ps[gi * 512 + k] * w;
  }
  for (int gi = 0; gi < 8; ++gi)
    O[(g0 + gi) * 256 + tid] = fmaxf(acc[gi], 0.f);
}

__global__ __launch_bounds__(128) void k_mlp2(const float* __restrict__ S,
    const float* __restrict__ W, const float* __restrict__ b, float* __restrict__ O) {
  __shared__ float Ss[16 * 256];
  int tid = threadIdx.x;
  int g0 = blockIdx.x * 16;
  for (int j = 0; j < 32; ++j) Ss[tid + j * 128] = S[g0 * 256 + tid + j * 128];
  __syncthreads();
  float acc[16];
  float bb = b[tid];
#pragma unroll
  for (int gi = 0; gi < 16; ++gi) acc[gi] = bb;
  for (int k = 0; k < 256; ++k) {
    float w = W[k * 128 + tid];
#pragma unroll
    for (int gi = 0; gi < 16; ++gi) acc[gi] += Ss[gi * 256 + k] * w;
  }
  for (int gi = 0; gi < 16; ++gi)
    O[(g0 + gi) * 128 + tid] = fmaxf(acc[gi], 0.f);
}

__global__ __launch_bounds__(128) void k_heads(const float* __restrict__ S,
    const float* __restrict__ hW1, const float* __restrict__ hb1,
    const float* __restrict__ hW2, const float* __restrict__ hb2,
    float* __restrict__ out) {
  __shared__ float ssm[128];
  __shared__ float t1[96];
  int g = blockIdx.x, tid = threadIdx.x;
  ssm[tid] = S[g * 128 + tid];
  __syncthreads();
  if (tid < 96) {
    int t = tid >> 5, o = tid & 31;
    float acc = hb1[t * 32 + o];
    for (int k = 0; k < 128; ++k) acc += ssm[k] * hW1[t * 4096 + k * 32 + o];
    t1[tid] = fmaxf(acc, 0.f);
  }
  __syncthreads();
  if (tid < 3) {
    float acc = hb2[tid];
    for (int o = 0; o < 32; ++o) acc += t1[tid * 32 + o] * hW2[tid * 32 + o];
    out[tid * NGRAPH + g] = acc;
  }
}

// ---------------- host launcher ----------------
extern "C" void kernel_launch(void* const* d_in, const int* in_sizes, int n_in,
                              void* d_out, int out_size, void* d_ws, size_t ws_size,
                              hipStream_t stream) {
  const float* x   = (const float*)d_in[0];
  const int* ei    = (const int*)d_in[1];
  const int* batch = (const int*)d_in[2];
  const float* W1 = (const float*)d_in[3];  const float* b1 = (const float*)d_in[4];
  const float* W2 = (const float*)d_in[5];  const float* b2 = (const float*)d_in[6];
  const float* W3 = (const float*)d_in[7];  const float* b3 = (const float*)d_in[8];
  const float* W4 = (const float*)d_in[9];  const float* b4 = (const float*)d_in[10];
  const float* g1 = (const float*)d_in[11]; const float* be1 = (const float*)d_in[12];
  const float* g2 = (const float*)d_in[13]; const float* be2 = (const float*)d_in[14];
  const float* g3 = (const float*)d_in[15]; const float* be3 = (const float*)d_in[16];
  const float* g4 = (const float*)d_in[17]; const float* be4 = (const float*)d_in[18];
  const float* sW1 = (const float*)d_in[19]; const float* sb1 = (const float*)d_in[20];
  const float* sW2 = (const float*)d_in[21]; const float* sb2 = (const float*)d_in[22];
  const float* hW1 = (const float*)d_in[23]; const float* hb1 = (const float*)d_in[24];
  const float* hW2 = (const float*)d_in[25]; const float* hb2 = (const float*)d_in[26];

  const int N = in_sizes[0] / 8;
  const int E = in_sizes[1] / 2;
  const int Npad = (N + 255) & ~255;
  const int* srcp = ei;
  const int* dstp = ei + E;

  char* base = (char*)d_ws;
  size_t off = 0;
  auto alloc = [&](size_t bytes) -> void* {
    void* p = base + off;
    off += (bytes + 255) & ~(size_t)255;
    return p;
  };
  unsigned short* Ybf = (unsigned short*)alloc((size_t)Npad * 256 * 2);
  unsigned short* Ahi = (unsigned short*)alloc((size_t)Npad * 256 * 2);
  float* dis  = (float*)alloc((size_t)N * 4);
  int* cnt    = (int*)alloc((size_t)N * 4);
  int* rs     = (int*)alloc((size_t)(N + 1) * 4);
  int* cursor = (int*)alloc((size_t)N * 4);
  int* es     = (int*)alloc((size_t)E * 4);
  int* bsum   = (int*)alloc(1024 * 4);
  int* bsumx  = (int*)alloc(1032 * 4);
  float* xa8  = (float*)alloc((size_t)N * 8 * 4);
  float* statsAll = (float*)alloc(2048 * 4);
  float* ssAll    = (float*)alloc(2048 * 4);
  unsigned short* Wthi = (unsigned short*)alloc(3 * 256 * 256 * 2);
  unsigned short* Wtlo = (unsigned short*)alloc(3 * 256 * 256 * 2);
  int* cntg    = (int*)alloc(2048 * 4);
  int* gstart  = (int*)alloc(2049 * 4);
  float* pooled = (float*)alloc((size_t)2048 * 512 * 4);
  float* s1b    = (float*)alloc((size_t)2048 * 256 * 4);
  float* s2b    = (float*)alloc((size_t)2048 * 128 * 4);
  (void)ws_size; (void)n_in; (void)out_size;

  int nb = (N + TPB - 1) / TPB;
  int eb = (E + TPB - 1) / TPB;
  int nblocks1 = (N + 1023) / 1024;

  k_init<<<nb, TPB, 0, stream>>>(dis, cnt, cntg, statsAll, N);
  k_deg_hist<<<eb, TPB, 0, stream>>>(dstp, dis, cnt, E);
  k_hist_batch<<<nb, TPB, 0, stream>>>(batch, cntg, N);
  k_rsqrt<<<nb, TPB, 0, stream>>>(dis, N);
  k_scan1<<<nblocks1, 256, 0, stream>>>(cnt, rs, bsum, N);
  k_scan_small<<<1, 256, 0, stream>>>(bsum, bsumx, nblocks1);
  k_scan3<<<nb, TPB, 0, stream>>>(rs, bsumx, cursor, N, E);
  k_scatter<<<eb, TPB, 0, stream>>>(srcp, dstp, cursor, es, E);
  k_scan_small<<<1, 256, 0, stream>>>(cntg, gstart, NGRAPH);

  // weight prep (layers 2..4)
  k_wprep<<<256, 256, 0, stream>>>(W2, Wthi + 0 * 65536, Wtlo + 0 * 65536);
  k_wprep<<<256, 256, 0, stream>>>(W3, Wthi + 1 * 65536, Wtlo + 1 * 65536);
  k_wprep<<<256, 256, 0, stream>>>(W4, Wthi + 2 * 65536, Wtlo + 2 * 65536);

  // ---- layer 1: aggregate on D=8, project (fp32), fused stats ----
  k_agg8<<<(N * 8 + TPB - 1) / TPB, TPB, 0, stream>>>(x, dis, rs, es, xa8, N);
  k_gemm8<<<(N + 63) / 64, 256, 0, stream>>>(xa8, W1, b1, Ybf, statsAll, N);
  k_scaleshift<<<1, 256, 0, stream>>>(statsAll, g1, be1, ssAll, N);

  // ---- layers 2..4 ----
  const float* bs_[3] = {b2, b3, b4};
  const float* gs[3]  = {g2, g3, g4};
  const float* bes[3] = {be2, be3, be4};
  for (int L = 0; L < 3; ++L) {
    k_agg_bn<<<(N + 3) / 4, 256, 0, stream>>>(Ybf, ssAll + L * 512, dis, rs, es,
                                              Ahi, N);
    k_gemm_mfma<<<Npad / 256, 512, 0, stream>>>(Ahi, Wthi + L * 65536, Wtlo + L * 65536,
                                                bs_[L], Ybf, statsAll + (L + 1) * 512, N);
    k_scaleshift<<<1, 256, 0, stream>>>(statsAll + (L + 1) * 512, gs[L], bes[L],
                                        ssAll + (L + 1) * 512, N);
  }

  // ---- pooling (fused BN+ReLU of layer 4) + MLP + heads ----
  k_pool<<<NGRAPH, 256, 0, stream>>>(Ybf, ssAll + 3 * 512, gstart, pooled);
  k_mlp1<<<NGRAPH / 8, 256, 0, stream>>>(pooled, sW1, sb1, s1b);
  k_mlp2<<<NGRAPH / 16, 128, 0, stream>>>(s1b, sW2, sb2, s2b);
  k_heads<<<NGRAPH, 128, 0, stream>>>(s2b, hW1, hb1, hW2, hb2, (float*)d_out);
}